// Round 14
// baseline (432.424 us; speedup 1.0000x reference)
//
#include <hip/hip_runtime.h>
#include <hip/hip_bf16.h>

#define NN 100000
#define NE 1600000
#define DIM 64
#define NG 64

#define NBUK 391      // coarse buckets of 256 nodes: bucket = col >> 8
#define EPB 4096      // edges per pass-1 block
#define NBLK 391      // ceil(NE/EPB)

static __device__ __forceinline__ unsigned short bf16bits(float v) {
    __hip_bfloat16 b = __float2bfloat16(v);
    return *reinterpret_cast<unsigned short*>(&b);
}
static __device__ __forceinline__ float bfbits2f(unsigned short u) {
    unsigned int x = ((unsigned int)u) << 16;
    return __uint_as_float(x);
}
// unpack packed bf16x2 dword -> two floats (lo = even dim, hi = odd dim)
static __device__ __forceinline__ void bf2x(unsigned int u, float& lo, float& hi) {
    lo = __uint_as_float(u << 16);
    hi = __uint_as_float(u & 0xFFFF0000u);
}

// ---------------- per-block bucket histogram (persisted) + global counts ----------
__global__ __launch_bounds__(1024) void k_ghist2(const int* __restrict__ col,
                                                 int* __restrict__ hist2d,
                                                 int* gcnt, int E) {
    __shared__ int hist[NBUK];
    int t = threadIdx.x;
    for (int i = t; i < NBUK; i += 1024) hist[i] = 0;
    __syncthreads();
    int e0 = blockIdx.x * EPB, e1 = min(e0 + EPB, E);
    for (int e = e0 + t; e < e1; e += 1024) atomicAdd(&hist[col[e] >> 8], 1);
    __syncthreads();
    for (int i = t; i < NBUK; i += 1024) {
        int c = hist[i];
        hist2d[blockIdx.x * NBUK + i] = c;
        if (c) atomicAdd(&gcnt[i], c);
    }
}

// ---------------- bucket offsets scan (one block) + zero pool buffers ----------
__global__ __launch_bounds__(256) void k_gscan(const int* __restrict__ gcnt,
                                               int* __restrict__ boff,
                                               float* __restrict__ sums,
                                               float* __restrict__ cntf) {
    __shared__ int sm[256];
    int t = threadIdx.x;
    for (int i = t; i < NG * DIM; i += 256) sums[i] = 0.f;
    if (t < NG) cntf[t] = 0.f;
    int v0 = (2 * t < NBUK) ? gcnt[2 * t] : 0;
    int v1 = (2 * t + 1 < NBUK) ? gcnt[2 * t + 1] : 0;
    int s = v0 + v1;
    sm[t] = s;
    __syncthreads();
    for (int off = 1; off < 256; off <<= 1) {
        int tmp = (t >= off) ? sm[t - off] : 0;
        __syncthreads();
        sm[t] += tmp;
        __syncthreads();
    }
    int run = sm[t] - s;
    if (2 * t < NBUK) boff[2 * t] = run;
    run += v0;
    if (2 * t + 1 < NBUK) boff[2 * t + 1] = run;
    if (t == 255) boff[NBUK] = run + v1;  // == NE
}

// ---------------- per-(block,bucket) base: scan hist2d column over blocks --------
__global__ __launch_bounds__(256) void k_colscan(const int* __restrict__ hist2d,
                                                 const int* __restrict__ boff,
                                                 int* __restrict__ base2d) {
    __shared__ int sm[256];
    int b = blockIdx.x, t = threadIdx.x;
    int v0 = (2 * t < NBLK) ? hist2d[(size_t)(2 * t) * NBUK + b] : 0;
    int v1 = (2 * t + 1 < NBLK) ? hist2d[(size_t)(2 * t + 1) * NBUK + b] : 0;
    int s = v0 + v1;
    sm[t] = s;
    __syncthreads();
    for (int off = 1; off < 256; off <<= 1) {
        int tmp = (t >= off) ? sm[t - off] : 0;
        __syncthreads();
        sm[t] += tmp;
        __syncthreads();
    }
    int run = boff[b] + sm[t] - s;
    if (2 * t < NBLK) base2d[(size_t)(2 * t) * NBUK + b] = run;
    run += v0;
    if (2 * t + 1 < NBLK) base2d[(size_t)(2 * t + 1) * NBUK + b] = run;
}

// ---------------- pass 1 v2: single pass, precomputed bases, no global atomics ----
// binned record: .x = (cl<<17)|row  (cl = col&255, row<2^17), .y = ew bits
__global__ __launch_bounds__(1024) void k_part1v2(const int* __restrict__ row,
                                                  const int* __restrict__ col,
                                                  const float* __restrict__ ew,
                                                  const int* __restrict__ base2d,
                                                  int2* __restrict__ binned, int E) {
    __shared__ int cur[NBUK];
    int t = threadIdx.x;
    for (int i = t; i < NBUK; i += 1024) cur[i] = base2d[(size_t)blockIdx.x * NBUK + i];
    __syncthreads();
    int e0 = blockIdx.x * EPB, e1 = min(e0 + EPB, E);
    for (int e = e0 + t; e < e1; e += 1024) {
        int c = col[e];
        int b = c >> 8, cl = c & 255;
        int p = atomicAdd(&cur[b], 1);
        binned[p] = make_int2((cl << 17) | row[e], __float_as_int(ew[e]));
    }
}

// ---------------- pass 2a: per-bucket degree (fixed-point) + rowptr + dinv --------
__global__ __launch_bounds__(256) void k_p2a(const int2* __restrict__ binned,
                                             const int* __restrict__ boff,
                                             float* __restrict__ dinv,
                                             int* __restrict__ rowptr) {
    int b = blockIdx.x, t = threadIdx.x;
    __shared__ unsigned int dsum[256];
    __shared__ int ncnt[256];
    __shared__ int sm[256];
    dsum[t] = 0;
    ncnt[t] = 0;
    __syncthreads();
    int e0 = boff[b], e1 = boff[b + 1];
    for (int e = e0 + t; e < e1; e += 256) {
        int2 v = binned[e];
        int cl = v.x >> 17;
        atomicAdd(&ncnt[cl], 1);
        unsigned int fx = (unsigned int)__float2uint_rn(__int_as_float(v.y) * 16777216.0f);
        atomicAdd(&dsum[cl], fx);
    }
    __syncthreads();
    int c = ncnt[t];
    sm[t] = c;
    __syncthreads();
    for (int off = 1; off < 256; off <<= 1) {
        int tmp = (t >= off) ? sm[t - off] : 0;
        __syncthreads();
        sm[t] += tmp;
        __syncthreads();
    }
    int node = b * 256 + t;
    if (node < NN) {
        rowptr[node] = e0 + sm[t] - c;
        dinv[node] = rsqrtf(1.0f + (float)dsum[t] * (1.0f / 16777216.0f));
    }
    if (b == 0 && t == 0) rowptr[NN] = NE;
}

// ---------------- pass 2b: per-bucket CSR place (contiguous window) ----------------
__global__ __launch_bounds__(256) void k_p2b(const int2* __restrict__ binned,
                                             const int* __restrict__ boff,
                                             const float* __restrict__ dinv,
                                             const int* __restrict__ rowptr,
                                             int2* __restrict__ csr) {
    int b = blockIdx.x, t = threadIdx.x;
    __shared__ int ncur[256];
    __shared__ float ldin[256];
    int node = b * 256 + t;
    ncur[t] = (node < NN) ? rowptr[node] : 0;
    ldin[t] = (node < NN) ? dinv[node] : 0.f;
    __syncthreads();
    int e0 = boff[b], e1 = boff[b + 1];
    for (int e = e0 + t; e < e1; e += 256) {
        int2 v = binned[e];
        int cl = v.x >> 17, r = v.x & 0x1FFFF;
        float nm = dinv[r] * __int_as_float(v.y) * ldin[cl];
        int p = atomicAdd(&ncur[cl], 1);
        csr[p] = make_int2(r, __float_as_int(nm));
    }
}

// ---------------- cast x -> bf16 ----------------
__global__ void k_cast(const float* __restrict__ x, unsigned short* __restrict__ xb, int nq) {
    int i = blockIdx.x * blockDim.x + threadIdx.x;
    if (i >= nq) return;
    float4 v = ((const float4*)x)[i];
    ushort4 o;
    o.x = bf16bits(v.x);
    o.y = bf16bits(v.y);
    o.z = bf16bits(v.z);
    o.w = bf16bits(v.w);
    ((ushort4*)xb)[i] = o;
}

// ---------------- gather v4: 4 nodes/wave, 2 groups/node, 4-deep csr pipeline ----
__global__ __launch_bounds__(256) void k_gather4(const int* __restrict__ rowptr,
                                                 const int2* __restrict__ csr,
                                                 const uint4* __restrict__ h8,
                                                 const float* __restrict__ dinv,
                                                 uint4* __restrict__ out, int n) {
    int tid = threadIdx.x;
    int node = blockIdx.x * 16 + (tid >> 4);
    if (node >= n) return;
    int l = tid & 15;
    int g2 = l >> 3, sub = l & 7;
    float acc[8];
#pragma unroll
    for (int i = 0; i < 8; ++i) acc[i] = 0.f;
    if (g2 == 0) {  // self-loop term (added once per node)
        float di = dinv[node];
        float s = di * di;
        uint4 v = h8[(size_t)node * 8 + sub];
        float lo, hi;
        bf2x(v.x, lo, hi); acc[0] = lo * s; acc[1] = hi * s;
        bf2x(v.y, lo, hi); acc[2] = lo * s; acc[3] = hi * s;
        bf2x(v.z, lo, hi); acc[4] = lo * s; acc[5] = hi * s;
        bf2x(v.w, lo, hi); acc[6] = lo * s; acc[7] = hi * s;
    }
    int e1 = rowptr[node + 1];
    int e = rowptr[node] + g2;
    int2 p[4];
#pragma unroll
    for (int i = 0; i < 4; ++i) {
        p[i] = make_int2(0, 0);
        if (e + 2 * i < e1) p[i] = csr[e + 2 * i];
    }
    while (e < e1) {
        uint4 r[4];
#pragma unroll
        for (int i = 0; i < 4; ++i) {
            r[i] = make_uint4(0u, 0u, 0u, 0u);
            if (e + 2 * i < e1) r[i] = h8[(size_t)p[i].x * 8 + sub];
        }
        int en = e + 8;
        int2 q[4];
#pragma unroll
        for (int i = 0; i < 4; ++i) {
            q[i] = make_int2(0, 0);
            if (en + 2 * i < e1) q[i] = csr[en + 2 * i];
        }
#pragma unroll
        for (int i = 0; i < 4; ++i) {
            float nm = __int_as_float(p[i].y);
            float lo, hi;
            bf2x(r[i].x, lo, hi); acc[0] = fmaf(lo, nm, acc[0]); acc[1] = fmaf(hi, nm, acc[1]);
            bf2x(r[i].y, lo, hi); acc[2] = fmaf(lo, nm, acc[2]); acc[3] = fmaf(hi, nm, acc[3]);
            bf2x(r[i].z, lo, hi); acc[4] = fmaf(lo, nm, acc[4]); acc[5] = fmaf(hi, nm, acc[5]);
            bf2x(r[i].w, lo, hi); acc[6] = fmaf(lo, nm, acc[6]); acc[7] = fmaf(hi, nm, acc[7]);
        }
#pragma unroll
        for (int i = 0; i < 4; ++i) p[i] = q[i];
        e = en;
    }
#pragma unroll
    for (int i = 0; i < 8; ++i) acc[i] += __shfl_xor(acc[i], 8);
    if (g2 == 0) {
        uint4 o;
        o.x = ((unsigned int)bf16bits(acc[1]) << 16) | bf16bits(acc[0]);
        o.y = ((unsigned int)bf16bits(acc[3]) << 16) | bf16bits(acc[2]);
        o.z = ((unsigned int)bf16bits(acc[5]) << 16) | bf16bits(acc[4]);
        o.w = ((unsigned int)bf16bits(acc[7]) << 16) | bf16bits(acc[6]);
        out[(size_t)node * 8 + sub] = o;
    }
}

// ---------------- GEMM v3: 64-node tile, 4x4 register tile, register-capped ------
__global__ __launch_bounds__(256, 4) void k_gemm64v3(const ushort4* __restrict__ in,
                                                     const float* __restrict__ W,
                                                     const float* __restrict__ b,
                                                     ushort4* __restrict__ out, int n) {
    __shared__ float sW[64][64];   // [k][d]
    __shared__ float sX[64][68];   // [node][k], +4 pad
    int tid = threadIdx.x;
#pragma unroll
    for (int i = 0; i < 4; ++i) {
        int q = tid + i * 256;
        ((float4*)&sW[0][0])[q] = ((const float4*)W)[q];
    }
    int base = blockIdx.x * 64;
#pragma unroll
    for (int i = 0; i < 4; ++i) {
        int idx = tid + i * 256;  // 0..1023
        int r = idx >> 4, q = idx & 15;
        int node = base + r;
        float4 f = make_float4(0.f, 0.f, 0.f, 0.f);
        if (node < n) {
            ushort4 v = in[(size_t)node * 16 + q];
            f.x = bfbits2f(v.x);
            f.y = bfbits2f(v.y);
            f.z = bfbits2f(v.z);
            f.w = bfbits2f(v.w);
        }
        *(float4*)&sX[r][q * 4] = f;
    }
    __syncthreads();
    int ng = tid >> 4;
    int dg = tid & 15;
    float acc[4][4];
#pragma unroll
    for (int i = 0; i < 4; ++i)
#pragma unroll
        for (int j = 0; j < 4; ++j) acc[i][j] = 0.f;
#pragma unroll 4
    for (int k4 = 0; k4 < 16; ++k4) {
        float4 xr[4];
#pragma unroll
        for (int i = 0; i < 4; ++i) xr[i] = *(const float4*)&sX[ng * 4 + i][k4 * 4];
        float4 wc[4];
#pragma unroll
        for (int j = 0; j < 4; ++j) wc[j] = *(const float4*)&sW[k4 * 4 + j][dg * 4];
#pragma unroll
        for (int i = 0; i < 4; ++i) {
            acc[i][0] = fmaf(xr[i].x, wc[0].x, acc[i][0]);
            acc[i][1] = fmaf(xr[i].x, wc[0].y, acc[i][1]);
            acc[i][2] = fmaf(xr[i].x, wc[0].z, acc[i][2]);
            acc[i][3] = fmaf(xr[i].x, wc[0].w, acc[i][3]);
            acc[i][0] = fmaf(xr[i].y, wc[1].x, acc[i][0]);
            acc[i][1] = fmaf(xr[i].y, wc[1].y, acc[i][1]);
            acc[i][2] = fmaf(xr[i].y, wc[1].z, acc[i][2]);
            acc[i][3] = fmaf(xr[i].y, wc[1].w, acc[i][3]);
            acc[i][0] = fmaf(xr[i].z, wc[2].x, acc[i][0]);
            acc[i][1] = fmaf(xr[i].z, wc[2].y, acc[i][1]);
            acc[i][2] = fmaf(xr[i].z, wc[2].z, acc[i][2]);
            acc[i][3] = fmaf(xr[i].z, wc[2].w, acc[i][3]);
            acc[i][0] = fmaf(xr[i].w, wc[3].x, acc[i][0]);
            acc[i][1] = fmaf(xr[i].w, wc[3].y, acc[i][1]);
            acc[i][2] = fmaf(xr[i].w, wc[3].z, acc[i][2]);
            acc[i][3] = fmaf(xr[i].w, wc[3].w, acc[i][3]);
        }
    }
    float4 bv = ((const float4*)b)[dg];
#pragma unroll
    for (int i = 0; i < 4; ++i) {
        int node = base + ng * 4 + i;
        if (node < n) {
            ushort4 o;
            o.x = bf16bits(fmaxf(acc[i][0] + bv.x, 0.f));
            o.y = bf16bits(fmaxf(acc[i][1] + bv.y, 0.f));
            o.z = bf16bits(fmaxf(acc[i][2] + bv.z, 0.f));
            o.w = bf16bits(fmaxf(acc[i][3] + bv.w, 0.f));
            out[(size_t)node * 16 + dg] = o;
        }
    }
}

// ---------------- pooling v2: bf16 input, 8-lane clusters, 16B loads ----------
// cluster = 8 lanes (sub = dim chunk of 8); each cluster owns 4 contiguous nodes.
#define PBLK 128  // nodes per block (32 clusters x 4 nodes)
__global__ __launch_bounds__(256) void k_pool2(const int* __restrict__ batch,
                                               const uint4* __restrict__ h8,
                                               float* sums, float* cnt, int n) {
    int t = threadIdx.x;
    int cl = t >> 3, sub = t & 7;
    int node0 = blockIdx.x * PBLK + cl * 4;
    float acc[8];
#pragma unroll
    for (int i = 0; i < 8; ++i) acc[i] = 0.f;
    int gcur = -1, runlen = 0;
    for (int j = 0; j < 4; ++j) {
        int node = node0 + j;
        if (node >= n) break;
        int g = batch[node];
        if (g != gcur) {
            if (gcur >= 0) {
                float* dst = &sums[gcur * DIM + sub * 8];
#pragma unroll
                for (int i = 0; i < 8; ++i) atomicAdd(dst + i, acc[i]);
                if (sub == 0) atomicAdd(&cnt[gcur], (float)runlen);
#pragma unroll
                for (int i = 0; i < 8; ++i) acc[i] = 0.f;
            }
            gcur = g;
            runlen = 0;
        }
        uint4 v = h8[(size_t)node * 8 + sub];
        float lo, hi;
        bf2x(v.x, lo, hi); acc[0] += lo; acc[1] += hi;
        bf2x(v.y, lo, hi); acc[2] += lo; acc[3] += hi;
        bf2x(v.z, lo, hi); acc[4] += lo; acc[5] += hi;
        bf2x(v.w, lo, hi); acc[6] += lo; acc[7] += hi;
        runlen++;
    }
    if (gcur >= 0) {
        float* dst = &sums[gcur * DIM + sub * 8];
#pragma unroll
        for (int i = 0; i < 8; ++i) atomicAdd(dst + i, acc[i]);
        if (sub == 0) atomicAdd(&cnt[gcur], (float)runlen);
    }
}

// ---------------- head: mean -> @W2+b2 -> fc1 relu -> fc2 -> out ----------------
__global__ __launch_bounds__(64) void k_head(const float* __restrict__ sums,
                                             const float* __restrict__ cnt,
                                             const float* __restrict__ W2,
                                             const float* __restrict__ b2,
                                             const float* __restrict__ fc1w,
                                             const float* __restrict__ fc1b,
                                             const float* __restrict__ fc2w,
                                             const float* __restrict__ fc2b,
                                             const float* __restrict__ ow,
                                             const float* __restrict__ ob,
                                             float* __restrict__ out) {
    int g = blockIdx.x;
    int t = threadIdx.x;
    __shared__ float gv[64];
    __shared__ float tv[64];
    float c = fmaxf(cnt[g], 1.0f);
    gv[t] = sums[g * DIM + t] / c;
    __syncthreads();
    float acc2 = b2[t];
#pragma unroll
    for (int k = 0; k < 64; ++k) acc2 = fmaf(gv[k], W2[k * 64 + t], acc2);
    tv[t] = acc2;
    __syncthreads();
    float r = 0.0f;
    if (t < 32) {
        float acc = fc1b[t];
#pragma unroll
        for (int k = 0; k < 64; ++k) acc = fmaf(tv[k], fc1w[k * 32 + t], acc);
        acc = fmaxf(acc, 0.0f);
        r = acc * fc2w[t];
    }
#pragma unroll
    for (int off = 16; off; off >>= 1) r += __shfl_down(r, off);
    if (t == 0) out[g] = (r + fc2b[0]) * ow[0] + ob[0];
}

extern "C" void kernel_launch(void* const* d_in, const int* in_sizes, int n_in,
                              void* d_out, int out_size, void* d_ws, size_t ws_size,
                              hipStream_t stream) {
    const float* x   = (const float*)d_in[0];
    const int* eidx  = (const int*)d_in[1];
    const float* ew  = (const float*)d_in[2];
    const int* batch = (const int*)d_in[3];
    const float* W0  = (const float*)d_in[4];
    const float* b0  = (const float*)d_in[5];
    const float* W1  = (const float*)d_in[6];
    const float* b1  = (const float*)d_in[7];
    const float* W2  = (const float*)d_in[8];
    const float* b2  = (const float*)d_in[9];
    const float* fc1w = (const float*)d_in[10];
    const float* fc1b = (const float*)d_in[11];
    const float* fc2w = (const float*)d_in[12];
    const float* fc2b = (const float*)d_in[13];
    const float* ow   = (const float*)d_in[14];
    const float* ob   = (const float*)d_in[15];
    float* out = (float*)d_out;

    const int* row = eidx;
    const int* col = eidx + NE;

    // workspace layout (16B-aligned blocks first)
    char* ws = (char*)d_ws;
    int2* binned           = (int2*)ws;               ws += sizeof(int2) * NE;                 // 12.8MB
    int2* csr              = (int2*)ws;               ws += sizeof(int2) * NE;                 // 12.8MB
    __hip_bfloat16* Xb     = (__hip_bfloat16*)ws;     ws += sizeof(__hip_bfloat16) * (size_t)NN * DIM;
    __hip_bfloat16* Hb     = (__hip_bfloat16*)ws;     ws += sizeof(__hip_bfloat16) * (size_t)NN * DIM;
    int*   hist2d          = (int*)ws;                ws += sizeof(int) * (size_t)NBLK * NBUK; // 611KB
    int*   base2d          = (int*)ws;                ws += sizeof(int) * (size_t)NBLK * NBUK; // 611KB
    float* dinv            = (float*)ws;              ws += sizeof(float) * NN;
    int*   rowptr          = (int*)ws;                ws += sizeof(int) * (NN + 1);
    int*   gcnt            = (int*)ws;                ws += sizeof(int) * (NBUK + 1);
    int*   boff            = (int*)ws;                ws += sizeof(int) * (NBUK + 1);
    float* sums            = (float*)ws;              ws += sizeof(float) * NG * DIM;
    float* cntf            = (float*)ws;              ws += sizeof(float) * NG;

    const int TB = 256;

    // ---- CSR build: persisted per-block hists + deterministic bases ----
    hipMemsetAsync(gcnt, 0, sizeof(int) * NBUK, stream);
    k_ghist2<<<NBLK, 1024, 0, stream>>>(col, hist2d, gcnt, NE);
    k_gscan<<<1, 256, 0, stream>>>(gcnt, boff, sums, cntf);
    k_colscan<<<NBUK, 256, 0, stream>>>(hist2d, boff, base2d);
    k_part1v2<<<NBLK, 1024, 0, stream>>>(row, col, ew, base2d, binned, NE);
    k_p2a<<<NBUK, 256, 0, stream>>>(binned, boff, dinv, rowptr);
    k_p2b<<<NBUK, 256, 0, stream>>>(binned, boff, dinv, rowptr, csr);

    // cast x -> bf16
    int nq = NN * DIM / 4;
    k_cast<<<(nq + TB - 1) / TB, TB, 0, stream>>>(x, (unsigned short*)Xb, nq);

    int gemm_blocks = (NN + 63) / 64;
    int gath_blocks = (NN + 15) / 16;

    // gather-first layers (bf16 pipeline): g = Ahat@X ; X' = relu(g @ W + b)
    k_gather4<<<gath_blocks, 256, 0, stream>>>(rowptr, csr, (const uint4*)Xb, dinv, (uint4*)Hb, NN);
    k_gemm64v3<<<gemm_blocks, 256, 0, stream>>>((const ushort4*)Hb, W0, b0, (ushort4*)Xb, NN);
    k_gather4<<<gath_blocks, 256, 0, stream>>>(rowptr, csr, (const uint4*)Xb, dinv, (uint4*)Hb, NN);
    k_gemm64v3<<<gemm_blocks, 256, 0, stream>>>((const ushort4*)Hb, W1, b1, (ushort4*)Xb, NN);
    k_gather4<<<gath_blocks, 256, 0, stream>>>(rowptr, csr, (const uint4*)Xb, dinv, (uint4*)Hb, NN);

    // pool over final gather (bf16); W2/b2 folded into head
    k_pool2<<<(NN + PBLK - 1) / PBLK, 256, 0, stream>>>(batch, (const uint4*)Hb, sums, cntf, NN);
    k_head<<<NG, 64, 0, stream>>>(sums, cntf, W2, b2, fc1w, fc1b, fc2w, fc2b, ow, ob, out);
}

// Round 15
// 229.107 us; speedup vs baseline: 1.8874x; 1.8874x over previous
//
#include <hip/hip_runtime.h>
#include <hip/hip_bf16.h>

#define NN 100000
#define NE 1600000
#define DIM 64
#define NG 64

#define NBUK 391      // coarse buckets of 256 nodes: bucket = col >> 8
#define EPB 4096      // edges per pass-1 block
#define NBLK 391      // ceil(NE/EPB)

static __device__ __forceinline__ unsigned short bf16bits(float v) {
    __hip_bfloat16 b = __float2bfloat16(v);
    return *reinterpret_cast<unsigned short*>(&b);
}
static __device__ __forceinline__ float bfbits2f(unsigned short u) {
    unsigned int x = ((unsigned int)u) << 16;
    return __uint_as_float(x);
}
// unpack packed bf16x2 dword -> two floats (lo = even dim, hi = odd dim)
static __device__ __forceinline__ void bf2x(unsigned int u, float& lo, float& hi) {
    lo = __uint_as_float(u << 16);
    hi = __uint_as_float(u & 0xFFFF0000u);
}

// ---------------- per-block bucket histogram (persisted) + global counts ----------
__global__ __launch_bounds__(1024) void k_ghist2(const int* __restrict__ col,
                                                 int* __restrict__ hist2d,
                                                 int* gcnt, int E) {
    __shared__ int hist[NBUK];
    int t = threadIdx.x;
    for (int i = t; i < NBUK; i += 1024) hist[i] = 0;
    __syncthreads();
    int e0 = blockIdx.x * EPB, e1 = min(e0 + EPB, E);
    for (int e = e0 + t; e < e1; e += 1024) atomicAdd(&hist[col[e] >> 8], 1);
    __syncthreads();
    for (int i = t; i < NBUK; i += 1024) {
        int c = hist[i];
        hist2d[blockIdx.x * NBUK + i] = c;
        if (c) atomicAdd(&gcnt[i], c);
    }
}

// ---------------- bucket offsets scan (one block) + zero pool buffers ----------
__global__ __launch_bounds__(256) void k_gscan(const int* __restrict__ gcnt,
                                               int* __restrict__ boff,
                                               float* __restrict__ sums,
                                               float* __restrict__ cntf) {
    __shared__ int sm[256];
    int t = threadIdx.x;
    for (int i = t; i < NG * DIM; i += 256) sums[i] = 0.f;
    if (t < NG) cntf[t] = 0.f;
    int v0 = (2 * t < NBUK) ? gcnt[2 * t] : 0;
    int v1 = (2 * t + 1 < NBUK) ? gcnt[2 * t + 1] : 0;
    int s = v0 + v1;
    sm[t] = s;
    __syncthreads();
    for (int off = 1; off < 256; off <<= 1) {
        int tmp = (t >= off) ? sm[t - off] : 0;
        __syncthreads();
        sm[t] += tmp;
        __syncthreads();
    }
    int run = sm[t] - s;
    if (2 * t < NBUK) boff[2 * t] = run;
    run += v0;
    if (2 * t + 1 < NBUK) boff[2 * t + 1] = run;
    if (t == 255) boff[NBUK] = run + v1;  // == NE
}

// ---------------- per-(block,bucket) base: scan hist2d column over blocks --------
__global__ __launch_bounds__(256) void k_colscan(const int* __restrict__ hist2d,
                                                 const int* __restrict__ boff,
                                                 int* __restrict__ base2d) {
    __shared__ int sm[256];
    int b = blockIdx.x, t = threadIdx.x;
    int v0 = (2 * t < NBLK) ? hist2d[(size_t)(2 * t) * NBUK + b] : 0;
    int v1 = (2 * t + 1 < NBLK) ? hist2d[(size_t)(2 * t + 1) * NBUK + b] : 0;
    int s = v0 + v1;
    sm[t] = s;
    __syncthreads();
    for (int off = 1; off < 256; off <<= 1) {
        int tmp = (t >= off) ? sm[t - off] : 0;
        __syncthreads();
        sm[t] += tmp;
        __syncthreads();
    }
    int run = boff[b] + sm[t] - s;
    if (2 * t < NBLK) base2d[(size_t)(2 * t) * NBUK + b] = run;
    run += v0;
    if (2 * t + 1 < NBLK) base2d[(size_t)(2 * t + 1) * NBUK + b] = run;
}

// ---------------- pass 1 v2: single pass, precomputed bases, no global atomics ----
// binned record: .x = (cl<<17)|row  (cl = col&255, row<2^17), .y = ew bits
__global__ __launch_bounds__(1024) void k_part1v2(const int* __restrict__ row,
                                                  const int* __restrict__ col,
                                                  const float* __restrict__ ew,
                                                  const int* __restrict__ base2d,
                                                  int2* __restrict__ binned, int E) {
    __shared__ int cur[NBUK];
    int t = threadIdx.x;
    for (int i = t; i < NBUK; i += 1024) cur[i] = base2d[(size_t)blockIdx.x * NBUK + i];
    __syncthreads();
    int e0 = blockIdx.x * EPB, e1 = min(e0 + EPB, E);
    for (int e = e0 + t; e < e1; e += 1024) {
        int c = col[e];
        int b = c >> 8, cl = c & 255;
        int p = atomicAdd(&cur[b], 1);
        binned[p] = make_int2((cl << 17) | row[e], __float_as_int(ew[e]));
    }
}

// ---------------- pass 2a: per-bucket degree (fixed-point) + rowptr + dinv --------
__global__ __launch_bounds__(256) void k_p2a(const int2* __restrict__ binned,
                                             const int* __restrict__ boff,
                                             float* __restrict__ dinv,
                                             int* __restrict__ rowptr) {
    int b = blockIdx.x, t = threadIdx.x;
    __shared__ unsigned int dsum[256];
    __shared__ int ncnt[256];
    __shared__ int sm[256];
    dsum[t] = 0;
    ncnt[t] = 0;
    __syncthreads();
    int e0 = boff[b], e1 = boff[b + 1];
    for (int e = e0 + t; e < e1; e += 256) {
        int2 v = binned[e];
        int cl = v.x >> 17;
        atomicAdd(&ncnt[cl], 1);
        unsigned int fx = (unsigned int)__float2uint_rn(__int_as_float(v.y) * 16777216.0f);
        atomicAdd(&dsum[cl], fx);
    }
    __syncthreads();
    int c = ncnt[t];
    sm[t] = c;
    __syncthreads();
    for (int off = 1; off < 256; off <<= 1) {
        int tmp = (t >= off) ? sm[t - off] : 0;
        __syncthreads();
        sm[t] += tmp;
        __syncthreads();
    }
    int node = b * 256 + t;
    if (node < NN) {
        rowptr[node] = e0 + sm[t] - c;
        dinv[node] = rsqrtf(1.0f + (float)dsum[t] * (1.0f / 16777216.0f));
    }
    if (b == 0 && t == 0) rowptr[NN] = NE;
}

// ---------------- pass 2b: per-bucket CSR place (contiguous window) ----------------
__global__ __launch_bounds__(256) void k_p2b(const int2* __restrict__ binned,
                                             const int* __restrict__ boff,
                                             const float* __restrict__ dinv,
                                             const int* __restrict__ rowptr,
                                             int2* __restrict__ csr) {
    int b = blockIdx.x, t = threadIdx.x;
    __shared__ int ncur[256];
    __shared__ float ldin[256];
    int node = b * 256 + t;
    ncur[t] = (node < NN) ? rowptr[node] : 0;
    ldin[t] = (node < NN) ? dinv[node] : 0.f;
    __syncthreads();
    int e0 = boff[b], e1 = boff[b + 1];
    for (int e = e0 + t; e < e1; e += 256) {
        int2 v = binned[e];
        int cl = v.x >> 17, r = v.x & 0x1FFFF;
        float nm = dinv[r] * __int_as_float(v.y) * ldin[cl];
        int p = atomicAdd(&ncur[cl], 1);
        csr[p] = make_int2(r, __float_as_int(nm));
    }
}

// ---------------- cast x -> bf16 ----------------
__global__ void k_cast(const float* __restrict__ x, unsigned short* __restrict__ xb, int nq) {
    int i = blockIdx.x * blockDim.x + threadIdx.x;
    if (i >= nq) return;
    float4 v = ((const float4*)x)[i];
    ushort4 o;
    o.x = bf16bits(v.x);
    o.y = bf16bits(v.y);
    o.z = bf16bits(v.z);
    o.w = bf16bits(v.w);
    ((ushort4*)xb)[i] = o;
}

// ---------------- gather v4: 4 nodes/wave, 2 groups/node, 4-deep csr pipeline ----
__global__ __launch_bounds__(256) void k_gather4(const int* __restrict__ rowptr,
                                                 const int2* __restrict__ csr,
                                                 const uint4* __restrict__ h8,
                                                 const float* __restrict__ dinv,
                                                 uint4* __restrict__ out, int n) {
    int tid = threadIdx.x;
    int node = blockIdx.x * 16 + (tid >> 4);
    if (node >= n) return;
    int l = tid & 15;
    int g2 = l >> 3, sub = l & 7;
    float acc[8];
#pragma unroll
    for (int i = 0; i < 8; ++i) acc[i] = 0.f;
    if (g2 == 0) {  // self-loop term (added once per node)
        float di = dinv[node];
        float s = di * di;
        uint4 v = h8[(size_t)node * 8 + sub];
        float lo, hi;
        bf2x(v.x, lo, hi); acc[0] = lo * s; acc[1] = hi * s;
        bf2x(v.y, lo, hi); acc[2] = lo * s; acc[3] = hi * s;
        bf2x(v.z, lo, hi); acc[4] = lo * s; acc[5] = hi * s;
        bf2x(v.w, lo, hi); acc[6] = lo * s; acc[7] = hi * s;
    }
    int e1 = rowptr[node + 1];
    int e = rowptr[node] + g2;
    int2 p[4];
#pragma unroll
    for (int i = 0; i < 4; ++i) {
        p[i] = make_int2(0, 0);
        if (e + 2 * i < e1) p[i] = csr[e + 2 * i];
    }
    while (e < e1) {
        uint4 r[4];
#pragma unroll
        for (int i = 0; i < 4; ++i) {
            r[i] = make_uint4(0u, 0u, 0u, 0u);
            if (e + 2 * i < e1) r[i] = h8[(size_t)p[i].x * 8 + sub];
        }
        int en = e + 8;
        int2 q[4];
#pragma unroll
        for (int i = 0; i < 4; ++i) {
            q[i] = make_int2(0, 0);
            if (en + 2 * i < e1) q[i] = csr[en + 2 * i];
        }
#pragma unroll
        for (int i = 0; i < 4; ++i) {
            float nm = __int_as_float(p[i].y);
            float lo, hi;
            bf2x(r[i].x, lo, hi); acc[0] = fmaf(lo, nm, acc[0]); acc[1] = fmaf(hi, nm, acc[1]);
            bf2x(r[i].y, lo, hi); acc[2] = fmaf(lo, nm, acc[2]); acc[3] = fmaf(hi, nm, acc[3]);
            bf2x(r[i].z, lo, hi); acc[4] = fmaf(lo, nm, acc[4]); acc[5] = fmaf(hi, nm, acc[5]);
            bf2x(r[i].w, lo, hi); acc[6] = fmaf(lo, nm, acc[6]); acc[7] = fmaf(hi, nm, acc[7]);
        }
#pragma unroll
        for (int i = 0; i < 4; ++i) p[i] = q[i];
        e = en;
    }
#pragma unroll
    for (int i = 0; i < 8; ++i) acc[i] += __shfl_xor(acc[i], 8);
    if (g2 == 0) {
        uint4 o;
        o.x = ((unsigned int)bf16bits(acc[1]) << 16) | bf16bits(acc[0]);
        o.y = ((unsigned int)bf16bits(acc[3]) << 16) | bf16bits(acc[2]);
        o.z = ((unsigned int)bf16bits(acc[5]) << 16) | bf16bits(acc[4]);
        o.w = ((unsigned int)bf16bits(acc[7]) << 16) | bf16bits(acc[6]);
        out[(size_t)node * 8 + sub] = o;
    }
}

// ---------------- GEMM v3: 64-node tile, 4x4 register tile, register-capped ------
__global__ __launch_bounds__(256, 4) void k_gemm64v3(const ushort4* __restrict__ in,
                                                     const float* __restrict__ W,
                                                     const float* __restrict__ b,
                                                     ushort4* __restrict__ out, int n) {
    __shared__ float sW[64][64];   // [k][d]
    __shared__ float sX[64][68];   // [node][k], +4 pad
    int tid = threadIdx.x;
#pragma unroll
    for (int i = 0; i < 4; ++i) {
        int q = tid + i * 256;
        ((float4*)&sW[0][0])[q] = ((const float4*)W)[q];
    }
    int base = blockIdx.x * 64;
#pragma unroll
    for (int i = 0; i < 4; ++i) {
        int idx = tid + i * 256;  // 0..1023
        int r = idx >> 4, q = idx & 15;
        int node = base + r;
        float4 f = make_float4(0.f, 0.f, 0.f, 0.f);
        if (node < n) {
            ushort4 v = in[(size_t)node * 16 + q];
            f.x = bfbits2f(v.x);
            f.y = bfbits2f(v.y);
            f.z = bfbits2f(v.z);
            f.w = bfbits2f(v.w);
        }
        *(float4*)&sX[r][q * 4] = f;
    }
    __syncthreads();
    int ng = tid >> 4;
    int dg = tid & 15;
    float acc[4][4];
#pragma unroll
    for (int i = 0; i < 4; ++i)
#pragma unroll
        for (int j = 0; j < 4; ++j) acc[i][j] = 0.f;
#pragma unroll 4
    for (int k4 = 0; k4 < 16; ++k4) {
        float4 xr[4];
#pragma unroll
        for (int i = 0; i < 4; ++i) xr[i] = *(const float4*)&sX[ng * 4 + i][k4 * 4];
        float4 wc[4];
#pragma unroll
        for (int j = 0; j < 4; ++j) wc[j] = *(const float4*)&sW[k4 * 4 + j][dg * 4];
#pragma unroll
        for (int i = 0; i < 4; ++i) {
            acc[i][0] = fmaf(xr[i].x, wc[0].x, acc[i][0]);
            acc[i][1] = fmaf(xr[i].x, wc[0].y, acc[i][1]);
            acc[i][2] = fmaf(xr[i].x, wc[0].z, acc[i][2]);
            acc[i][3] = fmaf(xr[i].x, wc[0].w, acc[i][3]);
            acc[i][0] = fmaf(xr[i].y, wc[1].x, acc[i][0]);
            acc[i][1] = fmaf(xr[i].y, wc[1].y, acc[i][1]);
            acc[i][2] = fmaf(xr[i].y, wc[1].z, acc[i][2]);
            acc[i][3] = fmaf(xr[i].y, wc[1].w, acc[i][3]);
            acc[i][0] = fmaf(xr[i].z, wc[2].x, acc[i][0]);
            acc[i][1] = fmaf(xr[i].z, wc[2].y, acc[i][1]);
            acc[i][2] = fmaf(xr[i].z, wc[2].z, acc[i][2]);
            acc[i][3] = fmaf(xr[i].z, wc[2].w, acc[i][3]);
            acc[i][0] = fmaf(xr[i].w, wc[3].x, acc[i][0]);
            acc[i][1] = fmaf(xr[i].w, wc[3].y, acc[i][1]);
            acc[i][2] = fmaf(xr[i].w, wc[3].z, acc[i][2]);
            acc[i][3] = fmaf(xr[i].w, wc[3].w, acc[i][3]);
        }
    }
    float4 bv = ((const float4*)b)[dg];
#pragma unroll
    for (int i = 0; i < 4; ++i) {
        int node = base + ng * 4 + i;
        if (node < n) {
            ushort4 o;
            o.x = bf16bits(fmaxf(acc[i][0] + bv.x, 0.f));
            o.y = bf16bits(fmaxf(acc[i][1] + bv.y, 0.f));
            o.z = bf16bits(fmaxf(acc[i][2] + bv.z, 0.f));
            o.w = bf16bits(fmaxf(acc[i][3] + bv.w, 0.f));
            out[(size_t)node * 16 + dg] = o;
        }
    }
}

// ---------------- pooling v3: LDS-staged two-level reduction ----------------
// Block owns PB3 contiguous nodes. Stage 1: 32 clusters x 8 lanes, uint4 reads,
// register run-merge -> LDS atomics. Stage 2: block's [g0..g1] group range
// (batch sorted) flushed with ngr*64 global atomics (~25k total).
#define PB3 512
__global__ __launch_bounds__(256) void k_pool3(const int* __restrict__ batch,
                                               const uint4* __restrict__ h8,
                                               float* sums, float* cnt, int n) {
    __shared__ float gsum[64][65];  // [group-g0][dim], +1 pad
    __shared__ float gcl[64];
    int t = threadIdx.x;
    for (int i = t; i < 64 * 65; i += 256) (&gsum[0][0])[i] = 0.f;
    if (t < 64) gcl[t] = 0.f;
    __syncthreads();
    int base = blockIdx.x * PB3;
    int end = min(base + PB3, n);
    int g0 = batch[base];
    int cl = t >> 3, sub = t & 7;
    float acc[8];
#pragma unroll
    for (int i = 0; i < 8; ++i) acc[i] = 0.f;
    int gcur = -1, runlen = 0;
    for (int node = base + cl; node < end; node += 32) {
        int g = batch[node];
        if (g != gcur) {
            if (gcur >= 0) {
                int gl = gcur - g0;
#pragma unroll
                for (int i = 0; i < 8; ++i) atomicAdd(&gsum[gl][sub * 8 + i], acc[i]);
                if (sub == 0) atomicAdd(&gcl[gl], (float)runlen);
#pragma unroll
                for (int i = 0; i < 8; ++i) acc[i] = 0.f;
            }
            gcur = g;
            runlen = 0;
        }
        uint4 v = h8[(size_t)node * 8 + sub];
        float lo, hi;
        bf2x(v.x, lo, hi); acc[0] += lo; acc[1] += hi;
        bf2x(v.y, lo, hi); acc[2] += lo; acc[3] += hi;
        bf2x(v.z, lo, hi); acc[4] += lo; acc[5] += hi;
        bf2x(v.w, lo, hi); acc[6] += lo; acc[7] += hi;
        runlen++;
    }
    if (gcur >= 0) {
        int gl = gcur - g0;
#pragma unroll
        for (int i = 0; i < 8; ++i) atomicAdd(&gsum[gl][sub * 8 + i], acc[i]);
        if (sub == 0) atomicAdd(&gcl[gl], (float)runlen);
    }
    __syncthreads();
    int g1 = batch[end - 1];
    int ngr = g1 - g0 + 1;
    for (int idx = t; idx < ngr * 64; idx += 256) {
        int gl = idx >> 6, d = idx & 63;
        float v = gsum[gl][d];
        if (v != 0.f) atomicAdd(&sums[(g0 + gl) * DIM + d], v);
    }
    if (t < ngr) {
        float c = gcl[t];
        if (c != 0.f) atomicAdd(&cnt[g0 + t], c);
    }
}

// ---------------- head: mean -> @W2+b2 -> fc1 relu -> fc2 -> out ----------------
__global__ __launch_bounds__(64) void k_head(const float* __restrict__ sums,
                                             const float* __restrict__ cnt,
                                             const float* __restrict__ W2,
                                             const float* __restrict__ b2,
                                             const float* __restrict__ fc1w,
                                             const float* __restrict__ fc1b,
                                             const float* __restrict__ fc2w,
                                             const float* __restrict__ fc2b,
                                             const float* __restrict__ ow,
                                             const float* __restrict__ ob,
                                             float* __restrict__ out) {
    int g = blockIdx.x;
    int t = threadIdx.x;
    __shared__ float gv[64];
    __shared__ float tv[64];
    float c = fmaxf(cnt[g], 1.0f);
    gv[t] = sums[g * DIM + t] / c;
    __syncthreads();
    float acc2 = b2[t];
#pragma unroll
    for (int k = 0; k < 64; ++k) acc2 = fmaf(gv[k], W2[k * 64 + t], acc2);
    tv[t] = acc2;
    __syncthreads();
    float r = 0.0f;
    if (t < 32) {
        float acc = fc1b[t];
#pragma unroll
        for (int k = 0; k < 64; ++k) acc = fmaf(tv[k], fc1w[k * 32 + t], acc);
        acc = fmaxf(acc, 0.0f);
        r = acc * fc2w[t];
    }
#pragma unroll
    for (int off = 16; off; off >>= 1) r += __shfl_down(r, off);
    if (t == 0) out[g] = (r + fc2b[0]) * ow[0] + ob[0];
}

extern "C" void kernel_launch(void* const* d_in, const int* in_sizes, int n_in,
                              void* d_out, int out_size, void* d_ws, size_t ws_size,
                              hipStream_t stream) {
    const float* x   = (const float*)d_in[0];
    const int* eidx  = (const int*)d_in[1];
    const float* ew  = (const float*)d_in[2];
    const int* batch = (const int*)d_in[3];
    const float* W0  = (const float*)d_in[4];
    const float* b0  = (const float*)d_in[5];
    const float* W1  = (const float*)d_in[6];
    const float* b1  = (const float*)d_in[7];
    const float* W2  = (const float*)d_in[8];
    const float* b2  = (const float*)d_in[9];
    const float* fc1w = (const float*)d_in[10];
    const float* fc1b = (const float*)d_in[11];
    const float* fc2w = (const float*)d_in[12];
    const float* fc2b = (const float*)d_in[13];
    const float* ow   = (const float*)d_in[14];
    const float* ob   = (const float*)d_in[15];
    float* out = (float*)d_out;

    const int* row = eidx;
    const int* col = eidx + NE;

    // workspace layout (16B-aligned blocks first)
    char* ws = (char*)d_ws;
    int2* binned           = (int2*)ws;               ws += sizeof(int2) * NE;                 // 12.8MB
    int2* csr              = (int2*)ws;               ws += sizeof(int2) * NE;                 // 12.8MB
    __hip_bfloat16* Xb     = (__hip_bfloat16*)ws;     ws += sizeof(__hip_bfloat16) * (size_t)NN * DIM;
    __hip_bfloat16* Hb     = (__hip_bfloat16*)ws;     ws += sizeof(__hip_bfloat16) * (size_t)NN * DIM;
    int*   hist2d          = (int*)ws;                ws += sizeof(int) * (size_t)NBLK * NBUK; // 611KB
    int*   base2d          = (int*)ws;                ws += sizeof(int) * (size_t)NBLK * NBUK; // 611KB
    float* dinv            = (float*)ws;              ws += sizeof(float) * NN;
    int*   rowptr          = (int*)ws;                ws += sizeof(int) * (NN + 1);
    int*   gcnt            = (int*)ws;                ws += sizeof(int) * (NBUK + 1);
    int*   boff            = (int*)ws;                ws += sizeof(int) * (NBUK + 1);
    float* sums            = (float*)ws;              ws += sizeof(float) * NG * DIM;
    float* cntf            = (float*)ws;              ws += sizeof(float) * NG;

    const int TB = 256;

    // ---- CSR build: persisted per-block hists + deterministic bases ----
    hipMemsetAsync(gcnt, 0, sizeof(int) * NBUK, stream);
    k_ghist2<<<NBLK, 1024, 0, stream>>>(col, hist2d, gcnt, NE);
    k_gscan<<<1, 256, 0, stream>>>(gcnt, boff, sums, cntf);
    k_colscan<<<NBUK, 256, 0, stream>>>(hist2d, boff, base2d);
    k_part1v2<<<NBLK, 1024, 0, stream>>>(row, col, ew, base2d, binned, NE);
    k_p2a<<<NBUK, 256, 0, stream>>>(binned, boff, dinv, rowptr);
    k_p2b<<<NBUK, 256, 0, stream>>>(binned, boff, dinv, rowptr, csr);

    // cast x -> bf16
    int nq = NN * DIM / 4;
    k_cast<<<(nq + TB - 1) / TB, TB, 0, stream>>>(x, (unsigned short*)Xb, nq);

    int gemm_blocks = (NN + 63) / 64;
    int gath_blocks = (NN + 15) / 16;

    // gather-first layers (bf16 pipeline): g = Ahat@X ; X' = relu(g @ W + b)
    k_gather4<<<gath_blocks, 256, 0, stream>>>(rowptr, csr, (const uint4*)Xb, dinv, (uint4*)Hb, NN);
    k_gemm64v3<<<gemm_blocks, 256, 0, stream>>>((const ushort4*)Hb, W0, b0, (ushort4*)Xb, NN);
    k_gather4<<<gath_blocks, 256, 0, stream>>>(rowptr, csr, (const uint4*)Xb, dinv, (uint4*)Hb, NN);
    k_gemm64v3<<<gemm_blocks, 256, 0, stream>>>((const ushort4*)Hb, W1, b1, (ushort4*)Xb, NN);
    k_gather4<<<gath_blocks, 256, 0, stream>>>(rowptr, csr, (const uint4*)Xb, dinv, (uint4*)Hb, NN);

    // pool over final gather (bf16, LDS-staged); W2/b2 folded into head
    k_pool3<<<(NN + PB3 - 1) / PB3, 256, 0, stream>>>(batch, (const uint4*)Hb, sums, cntf, NN);
    k_head<<<NG, 64, 0, stream>>>(sums, cntf, W2, b2, fc1w, fc1b, fc2w, fc2b, ow, ob, out);
}

// Round 16
// 224.609 us; speedup vs baseline: 1.9252x; 1.0200x over previous
//
#include <hip/hip_runtime.h>
#include <hip/hip_bf16.h>

#define NN 100000
#define NE 1600000
#define DIM 64
#define NG 64

#define NBUK 391      // coarse buckets of 256 nodes: bucket = col >> 8
#define EPB 4096      // edges per pass-1 block
#define NBLK 391      // ceil(NE/EPB)

static __device__ __forceinline__ unsigned short bf16bits(float v) {
    __hip_bfloat16 b = __float2bfloat16(v);
    return *reinterpret_cast<unsigned short*>(&b);
}
static __device__ __forceinline__ float bfbits2f(unsigned short u) {
    unsigned int x = ((unsigned int)u) << 16;
    return __uint_as_float(x);
}
// unpack packed bf16x2 dword -> two floats (lo = even dim, hi = odd dim)
static __device__ __forceinline__ void bf2x(unsigned int u, float& lo, float& hi) {
    lo = __uint_as_float(u << 16);
    hi = __uint_as_float(u & 0xFFFF0000u);
}
// csr pack: row(17 bits) | signless-bf16 nrm(15 bits). nrm >= 0 always.
static __device__ __forceinline__ unsigned csr_pack(int r, float nm) {
    unsigned u = __float_as_uint(nm);
    unsigned nb = ((u + 0x8000u) >> 16) & 0x7FFFu;  // round-to-nearest bf16, drop sign
    return ((unsigned)r << 15) | nb;
}
static __device__ __forceinline__ float csr_nrm(unsigned u) {
    return __uint_as_float((u & 0x7FFFu) << 16);
}

// ---------------- per-block bucket histogram (persisted) + global counts ----------
__global__ __launch_bounds__(1024) void k_ghist2(const int* __restrict__ col,
                                                 int* __restrict__ hist2d,
                                                 int* gcnt, int E) {
    __shared__ int hist[NBUK];
    int t = threadIdx.x;
    for (int i = t; i < NBUK; i += 1024) hist[i] = 0;
    __syncthreads();
    int e0 = blockIdx.x * EPB, e1 = min(e0 + EPB, E);
    for (int e = e0 + t; e < e1; e += 1024) atomicAdd(&hist[col[e] >> 8], 1);
    __syncthreads();
    for (int i = t; i < NBUK; i += 1024) {
        int c = hist[i];
        hist2d[blockIdx.x * NBUK + i] = c;
        if (c) atomicAdd(&gcnt[i], c);
    }
}

// ---------------- bucket offsets scan (one block) + zero pool buffers ----------
__global__ __launch_bounds__(256) void k_gscan(const int* __restrict__ gcnt,
                                               int* __restrict__ boff,
                                               float* __restrict__ sums,
                                               float* __restrict__ cntf) {
    __shared__ int sm[256];
    int t = threadIdx.x;
    for (int i = t; i < NG * DIM; i += 256) sums[i] = 0.f;
    if (t < NG) cntf[t] = 0.f;
    int v0 = (2 * t < NBUK) ? gcnt[2 * t] : 0;
    int v1 = (2 * t + 1 < NBUK) ? gcnt[2 * t + 1] : 0;
    int s = v0 + v1;
    sm[t] = s;
    __syncthreads();
    for (int off = 1; off < 256; off <<= 1) {
        int tmp = (t >= off) ? sm[t - off] : 0;
        __syncthreads();
        sm[t] += tmp;
        __syncthreads();
    }
    int run = sm[t] - s;
    if (2 * t < NBUK) boff[2 * t] = run;
    run += v0;
    if (2 * t + 1 < NBUK) boff[2 * t + 1] = run;
    if (t == 255) boff[NBUK] = run + v1;  // == NE
}

// ---------------- per-(block,bucket) base scan + fused x->bf16 cast --------------
__global__ __launch_bounds__(256) void k_colscan(const int* __restrict__ hist2d,
                                                 const int* __restrict__ boff,
                                                 int* __restrict__ base2d,
                                                 const float* __restrict__ x,
                                                 unsigned short* __restrict__ xb) {
    __shared__ int sm[256];
    int b = blockIdx.x, t = threadIdx.x;
    int v0 = (2 * t < NBLK) ? hist2d[(size_t)(2 * t) * NBUK + b] : 0;
    int v1 = (2 * t + 1 < NBLK) ? hist2d[(size_t)(2 * t + 1) * NBUK + b] : 0;
    int s = v0 + v1;
    sm[t] = s;
    __syncthreads();
    for (int off = 1; off < 256; off <<= 1) {
        int tmp = (t >= off) ? sm[t - off] : 0;
        __syncthreads();
        sm[t] += tmp;
        __syncthreads();
    }
    int run = boff[b] + sm[t] - s;
    if (2 * t < NBLK) base2d[(size_t)(2 * t) * NBUK + b] = run;
    run += v0;
    if (2 * t + 1 < NBLK) base2d[(size_t)(2 * t + 1) * NBUK + b] = run;
    // fused cast: block b converts its slice of x (float4 quads)
    const int NQ = NN * DIM / 4;
    const int per = (NQ + NBLK - 1) / NBLK;
    int q0 = b * per, q1 = min(q0 + per, NQ);
    for (int i = q0 + t; i < q1; i += 256) {
        float4 v = ((const float4*)x)[i];
        ushort4 o;
        o.x = bf16bits(v.x);
        o.y = bf16bits(v.y);
        o.z = bf16bits(v.z);
        o.w = bf16bits(v.w);
        ((ushort4*)xb)[i] = o;
    }
}

// ---------------- pass 1 v2: single pass, precomputed bases, no global atomics ----
// binned record: .x = (cl<<17)|row  (cl = col&255, row<2^17), .y = ew bits
__global__ __launch_bounds__(1024) void k_part1v2(const int* __restrict__ row,
                                                  const int* __restrict__ col,
                                                  const float* __restrict__ ew,
                                                  const int* __restrict__ base2d,
                                                  int2* __restrict__ binned, int E) {
    __shared__ int cur[NBUK];
    int t = threadIdx.x;
    for (int i = t; i < NBUK; i += 1024) cur[i] = base2d[(size_t)blockIdx.x * NBUK + i];
    __syncthreads();
    int e0 = blockIdx.x * EPB, e1 = min(e0 + EPB, E);
    for (int e = e0 + t; e < e1; e += 1024) {
        int c = col[e];
        int b = c >> 8, cl = c & 255;
        int p = atomicAdd(&cur[b], 1);
        binned[p] = make_int2((cl << 17) | row[e], __float_as_int(ew[e]));
    }
}

// ---------------- pass 2a: per-bucket degree (fixed-point) + rowptr + dinv --------
__global__ __launch_bounds__(256) void k_p2a(const int2* __restrict__ binned,
                                             const int* __restrict__ boff,
                                             float* __restrict__ dinv,
                                             int* __restrict__ rowptr) {
    int b = blockIdx.x, t = threadIdx.x;
    __shared__ unsigned int dsum[256];
    __shared__ int ncnt[256];
    __shared__ int sm[256];
    dsum[t] = 0;
    ncnt[t] = 0;
    __syncthreads();
    int e0 = boff[b], e1 = boff[b + 1];
    for (int e = e0 + t; e < e1; e += 256) {
        int2 v = binned[e];
        int cl = v.x >> 17;
        atomicAdd(&ncnt[cl], 1);
        unsigned int fx = (unsigned int)__float2uint_rn(__int_as_float(v.y) * 16777216.0f);
        atomicAdd(&dsum[cl], fx);
    }
    __syncthreads();
    int c = ncnt[t];
    sm[t] = c;
    __syncthreads();
    for (int off = 1; off < 256; off <<= 1) {
        int tmp = (t >= off) ? sm[t - off] : 0;
        __syncthreads();
        sm[t] += tmp;
        __syncthreads();
    }
    int node = b * 256 + t;
    if (node < NN) {
        rowptr[node] = e0 + sm[t] - c;
        dinv[node] = rsqrtf(1.0f + (float)dsum[t] * (1.0f / 16777216.0f));
    }
    if (b == 0 && t == 0) rowptr[NN] = NE;
}

// ---------------- pass 2b: per-bucket CSR place (packed 4B records) ----------------
__global__ __launch_bounds__(256) void k_p2b(const int2* __restrict__ binned,
                                             const int* __restrict__ boff,
                                             const float* __restrict__ dinv,
                                             const int* __restrict__ rowptr,
                                             unsigned* __restrict__ csr) {
    int b = blockIdx.x, t = threadIdx.x;
    __shared__ int ncur[256];
    __shared__ float ldin[256];
    int node = b * 256 + t;
    ncur[t] = (node < NN) ? rowptr[node] : 0;
    ldin[t] = (node < NN) ? dinv[node] : 0.f;
    __syncthreads();
    int e0 = boff[b], e1 = boff[b + 1];
    for (int e = e0 + t; e < e1; e += 256) {
        int2 v = binned[e];
        int cl = v.x >> 17, r = v.x & 0x1FFFF;
        float nm = dinv[r] * __int_as_float(v.y) * ldin[cl];
        int p = atomicAdd(&ncur[cl], 1);
        csr[p] = csr_pack(r, nm);
    }
}

// ---------------- gather v5: packed 4B csr, 4 nodes/wave, 4-deep pipeline ----------
__global__ __launch_bounds__(256) void k_gather5(const int* __restrict__ rowptr,
                                                 const unsigned* __restrict__ csr,
                                                 const uint4* __restrict__ h8,
                                                 const float* __restrict__ dinv,
                                                 uint4* __restrict__ out, int n) {
    int tid = threadIdx.x;
    int node = blockIdx.x * 16 + (tid >> 4);
    if (node >= n) return;
    int l = tid & 15;
    int g2 = l >> 3, sub = l & 7;
    float acc[8];
#pragma unroll
    for (int i = 0; i < 8; ++i) acc[i] = 0.f;
    if (g2 == 0) {  // self-loop term (added once per node)
        float di = dinv[node];
        float s = di * di;
        uint4 v = h8[(size_t)node * 8 + sub];
        float lo, hi;
        bf2x(v.x, lo, hi); acc[0] = lo * s; acc[1] = hi * s;
        bf2x(v.y, lo, hi); acc[2] = lo * s; acc[3] = hi * s;
        bf2x(v.z, lo, hi); acc[4] = lo * s; acc[5] = hi * s;
        bf2x(v.w, lo, hi); acc[6] = lo * s; acc[7] = hi * s;
    }
    int e1 = rowptr[node + 1];
    int e = rowptr[node] + g2;
    unsigned p[4];
#pragma unroll
    for (int i = 0; i < 4; ++i) {
        p[i] = 0u;
        if (e + 2 * i < e1) p[i] = csr[e + 2 * i];
    }
    while (e < e1) {
        uint4 r[4];
#pragma unroll
        for (int i = 0; i < 4; ++i) {
            r[i] = make_uint4(0u, 0u, 0u, 0u);
            if (e + 2 * i < e1) r[i] = h8[(size_t)(p[i] >> 15) * 8 + sub];
        }
        int en = e + 8;
        unsigned q[4];
#pragma unroll
        for (int i = 0; i < 4; ++i) {
            q[i] = 0u;
            if (en + 2 * i < e1) q[i] = csr[en + 2 * i];
        }
#pragma unroll
        for (int i = 0; i < 4; ++i) {
            float nm = csr_nrm(p[i]);
            float lo, hi;
            bf2x(r[i].x, lo, hi); acc[0] = fmaf(lo, nm, acc[0]); acc[1] = fmaf(hi, nm, acc[1]);
            bf2x(r[i].y, lo, hi); acc[2] = fmaf(lo, nm, acc[2]); acc[3] = fmaf(hi, nm, acc[3]);
            bf2x(r[i].z, lo, hi); acc[4] = fmaf(lo, nm, acc[4]); acc[5] = fmaf(hi, nm, acc[5]);
            bf2x(r[i].w, lo, hi); acc[6] = fmaf(lo, nm, acc[6]); acc[7] = fmaf(hi, nm, acc[7]);
        }
#pragma unroll
        for (int i = 0; i < 4; ++i) p[i] = q[i];
        e = en;
    }
#pragma unroll
    for (int i = 0; i < 8; ++i) acc[i] += __shfl_xor(acc[i], 8);
    if (g2 == 0) {
        uint4 o;
        o.x = ((unsigned int)bf16bits(acc[1]) << 16) | bf16bits(acc[0]);
        o.y = ((unsigned int)bf16bits(acc[3]) << 16) | bf16bits(acc[2]);
        o.z = ((unsigned int)bf16bits(acc[5]) << 16) | bf16bits(acc[4]);
        o.w = ((unsigned int)bf16bits(acc[7]) << 16) | bf16bits(acc[6]);
        out[(size_t)node * 8 + sub] = o;
    }
}

// ---------------- GEMM v3: 64-node tile, 4x4 register tile, register-capped ------
__global__ __launch_bounds__(256, 4) void k_gemm64v3(const ushort4* __restrict__ in,
                                                     const float* __restrict__ W,
                                                     const float* __restrict__ b,
                                                     ushort4* __restrict__ out, int n) {
    __shared__ float sW[64][64];   // [k][d]
    __shared__ float sX[64][68];   // [node][k], +4 pad
    int tid = threadIdx.x;
#pragma unroll
    for (int i = 0; i < 4; ++i) {
        int q = tid + i * 256;
        ((float4*)&sW[0][0])[q] = ((const float4*)W)[q];
    }
    int base = blockIdx.x * 64;
#pragma unroll
    for (int i = 0; i < 4; ++i) {
        int idx = tid + i * 256;  // 0..1023
        int r = idx >> 4, q = idx & 15;
        int node = base + r;
        float4 f = make_float4(0.f, 0.f, 0.f, 0.f);
        if (node < n) {
            ushort4 v = in[(size_t)node * 16 + q];
            f.x = bfbits2f(v.x);
            f.y = bfbits2f(v.y);
            f.z = bfbits2f(v.z);
            f.w = bfbits2f(v.w);
        }
        *(float4*)&sX[r][q * 4] = f;
    }
    __syncthreads();
    int ng = tid >> 4;
    int dg = tid & 15;
    float acc[4][4];
#pragma unroll
    for (int i = 0; i < 4; ++i)
#pragma unroll
        for (int j = 0; j < 4; ++j) acc[i][j] = 0.f;
#pragma unroll 4
    for (int k4 = 0; k4 < 16; ++k4) {
        float4 xr[4];
#pragma unroll
        for (int i = 0; i < 4; ++i) xr[i] = *(const float4*)&sX[ng * 4 + i][k4 * 4];
        float4 wc[4];
#pragma unroll
        for (int j = 0; j < 4; ++j) wc[j] = *(const float4*)&sW[k4 * 4 + j][dg * 4];
#pragma unroll
        for (int i = 0; i < 4; ++i) {
            acc[i][0] = fmaf(xr[i].x, wc[0].x, acc[i][0]);
            acc[i][1] = fmaf(xr[i].x, wc[0].y, acc[i][1]);
            acc[i][2] = fmaf(xr[i].x, wc[0].z, acc[i][2]);
            acc[i][3] = fmaf(xr[i].x, wc[0].w, acc[i][3]);
            acc[i][0] = fmaf(xr[i].y, wc[1].x, acc[i][0]);
            acc[i][1] = fmaf(xr[i].y, wc[1].y, acc[i][1]);
            acc[i][2] = fmaf(xr[i].y, wc[1].z, acc[i][2]);
            acc[i][3] = fmaf(xr[i].y, wc[1].w, acc[i][3]);
            acc[i][0] = fmaf(xr[i].z, wc[2].x, acc[i][0]);
            acc[i][1] = fmaf(xr[i].z, wc[2].y, acc[i][1]);
            acc[i][2] = fmaf(xr[i].z, wc[2].z, acc[i][2]);
            acc[i][3] = fmaf(xr[i].z, wc[2].w, acc[i][3]);
            acc[i][0] = fmaf(xr[i].w, wc[3].x, acc[i][0]);
            acc[i][1] = fmaf(xr[i].w, wc[3].y, acc[i][1]);
            acc[i][2] = fmaf(xr[i].w, wc[3].z, acc[i][2]);
            acc[i][3] = fmaf(xr[i].w, wc[3].w, acc[i][3]);
        }
    }
    float4 bv = ((const float4*)b)[dg];
#pragma unroll
    for (int i = 0; i < 4; ++i) {
        int node = base + ng * 4 + i;
        if (node < n) {
            ushort4 o;
            o.x = bf16bits(fmaxf(acc[i][0] + bv.x, 0.f));
            o.y = bf16bits(fmaxf(acc[i][1] + bv.y, 0.f));
            o.z = bf16bits(fmaxf(acc[i][2] + bv.z, 0.f));
            o.w = bf16bits(fmaxf(acc[i][3] + bv.w, 0.f));
            out[(size_t)node * 16 + dg] = o;
        }
    }
}

// ---------------- pooling v3: LDS-staged two-level reduction ----------------
#define PB3 512
__global__ __launch_bounds__(256) void k_pool3(const int* __restrict__ batch,
                                               const uint4* __restrict__ h8,
                                               float* sums, float* cnt, int n) {
    __shared__ float gsum[64][65];  // [group-g0][dim], +1 pad
    __shared__ float gcl[64];
    int t = threadIdx.x;
    for (int i = t; i < 64 * 65; i += 256) (&gsum[0][0])[i] = 0.f;
    if (t < 64) gcl[t] = 0.f;
    __syncthreads();
    int base = blockIdx.x * PB3;
    int end = min(base + PB3, n);
    int g0 = batch[base];
    int cl = t >> 3, sub = t & 7;
    float acc[8];
#pragma unroll
    for (int i = 0; i < 8; ++i) acc[i] = 0.f;
    int gcur = -1, runlen = 0;
    for (int node = base + cl; node < end; node += 32) {
        int g = batch[node];
        if (g != gcur) {
            if (gcur >= 0) {
                int gl = gcur - g0;
#pragma unroll
                for (int i = 0; i < 8; ++i) atomicAdd(&gsum[gl][sub * 8 + i], acc[i]);
                if (sub == 0) atomicAdd(&gcl[gl], (float)runlen);
#pragma unroll
                for (int i = 0; i < 8; ++i) acc[i] = 0.f;
            }
            gcur = g;
            runlen = 0;
        }
        uint4 v = h8[(size_t)node * 8 + sub];
        float lo, hi;
        bf2x(v.x, lo, hi); acc[0] += lo; acc[1] += hi;
        bf2x(v.y, lo, hi); acc[2] += lo; acc[3] += hi;
        bf2x(v.z, lo, hi); acc[4] += lo; acc[5] += hi;
        bf2x(v.w, lo, hi); acc[6] += lo; acc[7] += hi;
        runlen++;
    }
    if (gcur >= 0) {
        int gl = gcur - g0;
#pragma unroll
        for (int i = 0; i < 8; ++i) atomicAdd(&gsum[gl][sub * 8 + i], acc[i]);
        if (sub == 0) atomicAdd(&gcl[gl], (float)runlen);
    }
    __syncthreads();
    int g1 = batch[end - 1];
    int ngr = g1 - g0 + 1;
    for (int idx = t; idx < ngr * 64; idx += 256) {
        int gl = idx >> 6, d = idx & 63;
        float v = gsum[gl][d];
        if (v != 0.f) atomicAdd(&sums[(g0 + gl) * DIM + d], v);
    }
    if (t < ngr) {
        float c = gcl[t];
        if (c != 0.f) atomicAdd(&cnt[g0 + t], c);
    }
}

// ---------------- head: mean -> @W2+b2 -> fc1 relu -> fc2 -> out ----------------
__global__ __launch_bounds__(64) void k_head(const float* __restrict__ sums,
                                             const float* __restrict__ cnt,
                                             const float* __restrict__ W2,
                                             const float* __restrict__ b2,
                                             const float* __restrict__ fc1w,
                                             const float* __restrict__ fc1b,
                                             const float* __restrict__ fc2w,
                                             const float* __restrict__ fc2b,
                                             const float* __restrict__ ow,
                                             const float* __restrict__ ob,
                                             float* __restrict__ out) {
    int g = blockIdx.x;
    int t = threadIdx.x;
    __shared__ float gv[64];
    __shared__ float tv[64];
    float c = fmaxf(cnt[g], 1.0f);
    gv[t] = sums[g * DIM + t] / c;
    __syncthreads();
    float acc2 = b2[t];
#pragma unroll
    for (int k = 0; k < 64; ++k) acc2 = fmaf(gv[k], W2[k * 64 + t], acc2);
    tv[t] = acc2;
    __syncthreads();
    float r = 0.0f;
    if (t < 32) {
        float acc = fc1b[t];
#pragma unroll
        for (int k = 0; k < 64; ++k) acc = fmaf(tv[k], fc1w[k * 32 + t], acc);
        acc = fmaxf(acc, 0.0f);
        r = acc * fc2w[t];
    }
#pragma unroll
    for (int off = 16; off; off >>= 1) r += __shfl_down(r, off);
    if (t == 0) out[g] = (r + fc2b[0]) * ow[0] + ob[0];
}

extern "C" void kernel_launch(void* const* d_in, const int* in_sizes, int n_in,
                              void* d_out, int out_size, void* d_ws, size_t ws_size,
                              hipStream_t stream) {
    const float* x   = (const float*)d_in[0];
    const int* eidx  = (const int*)d_in[1];
    const float* ew  = (const float*)d_in[2];
    const int* batch = (const int*)d_in[3];
    const float* W0  = (const float*)d_in[4];
    const float* b0  = (const float*)d_in[5];
    const float* W1  = (const float*)d_in[6];
    const float* b1  = (const float*)d_in[7];
    const float* W2  = (const float*)d_in[8];
    const float* b2  = (const float*)d_in[9];
    const float* fc1w = (const float*)d_in[10];
    const float* fc1b = (const float*)d_in[11];
    const float* fc2w = (const float*)d_in[12];
    const float* fc2b = (const float*)d_in[13];
    const float* ow   = (const float*)d_in[14];
    const float* ob   = (const float*)d_in[15];
    float* out = (float*)d_out;

    const int* row = eidx;
    const int* col = eidx + NE;

    // workspace layout (16B-aligned blocks first)
    char* ws = (char*)d_ws;
    int2* binned           = (int2*)ws;               ws += sizeof(int2) * NE;                 // 12.8MB
    unsigned* csr          = (unsigned*)ws;           ws += sizeof(unsigned) * NE;             // 6.4MB
    __hip_bfloat16* Xb     = (__hip_bfloat16*)ws;     ws += sizeof(__hip_bfloat16) * (size_t)NN * DIM;
    __hip_bfloat16* Hb     = (__hip_bfloat16*)ws;     ws += sizeof(__hip_bfloat16) * (size_t)NN * DIM;
    int*   hist2d          = (int*)ws;                ws += sizeof(int) * (size_t)NBLK * NBUK; // 611KB
    int*   base2d          = (int*)ws;                ws += sizeof(int) * (size_t)NBLK * NBUK; // 611KB
    float* dinv            = (float*)ws;              ws += sizeof(float) * NN;
    int*   rowptr          = (int*)ws;                ws += sizeof(int) * (NN + 1);
    int*   gcnt            = (int*)ws;                ws += sizeof(int) * (NBUK + 1);
    int*   boff            = (int*)ws;                ws += sizeof(int) * (NBUK + 1);
    float* sums            = (float*)ws;              ws += sizeof(float) * NG * DIM;
    float* cntf            = (float*)ws;              ws += sizeof(float) * NG;

    // ---- CSR build: persisted per-block hists + deterministic bases ----
    hipMemsetAsync(gcnt, 0, sizeof(int) * NBUK, stream);
    k_ghist2<<<NBLK, 1024, 0, stream>>>(col, hist2d, gcnt, NE);
    k_gscan<<<1, 256, 0, stream>>>(gcnt, boff, sums, cntf);
    k_colscan<<<NBUK, 256, 0, stream>>>(hist2d, boff, base2d, x, (unsigned short*)Xb);
    k_part1v2<<<NBLK, 1024, 0, stream>>>(row, col, ew, base2d, binned, NE);
    k_p2a<<<NBUK, 256, 0, stream>>>(binned, boff, dinv, rowptr);
    k_p2b<<<NBUK, 256, 0, stream>>>(binned, boff, dinv, rowptr, csr);

    int gemm_blocks = (NN + 63) / 64;
    int gath_blocks = (NN + 15) / 16;

    // gather-first layers (bf16 pipeline): g = Ahat@X ; X' = relu(g @ W + b)
    k_gather5<<<gath_blocks, 256, 0, stream>>>(rowptr, csr, (const uint4*)Xb, dinv, (uint4*)Hb, NN);
    k_gemm64v3<<<gemm_blocks, 256, 0, stream>>>((const ushort4*)Hb, W0, b0, (ushort4*)Xb, NN);
    k_gather5<<<gath_blocks, 256, 0, stream>>>(rowptr, csr, (const uint4*)Xb, dinv, (uint4*)Hb, NN);
    k_gemm64v3<<<gemm_blocks, 256, 0, stream>>>((const ushort4*)Hb, W1, b1, (ushort4*)Xb, NN);
    k_gather5<<<gath_blocks, 256, 0, stream>>>(rowptr, csr, (const uint4*)Xb, dinv, (uint4*)Hb, NN);

    // pool over final gather (bf16, LDS-staged); W2/b2 folded into head
    k_pool3<<<(NN + PB3 - 1) / PB3, 256, 0, stream>>>(batch, (const uint4*)Hb, sums, cntf, NN);
    k_head<<<NG, 64, 0, stream>>>(sums, cntf, W2, b2, fc1w, fc1b, fc2w, fc2b, ow, ob, out);
}

// Round 17
// 197.882 us; speedup vs baseline: 2.1853x; 1.1351x over previous
//
#include <hip/hip_runtime.h>
#include <hip/hip_bf16.h>

#define NN 100000
#define NE 1600000
#define DIM 64
#define NG 64

#define NBUK 391      // coarse buckets of 256 nodes: bucket = col >> 8
#define EPB 4096      // edges per pass-1 block
#define NBLK 391      // ceil(NE/EPB)

static __device__ __forceinline__ unsigned short bf16bits(float v) {
    __hip_bfloat16 b = __float2bfloat16(v);
    return *reinterpret_cast<unsigned short*>(&b);
}
static __device__ __forceinline__ float bfbits2f(unsigned short u) {
    unsigned int x = ((unsigned int)u) << 16;
    return __uint_as_float(x);
}
// unpack packed bf16x2 dword -> two floats (lo = even dim, hi = odd dim)
static __device__ __forceinline__ void bf2x(unsigned int u, float& lo, float& hi) {
    lo = __uint_as_float(u << 16);
    hi = __uint_as_float(u & 0xFFFF0000u);
}
// csr pack: row(17 bits) | signless-bf16 nrm(15 bits). nrm >= 0 always.
static __device__ __forceinline__ unsigned csr_pack(int r, float nm) {
    unsigned u = __float_as_uint(nm);
    unsigned nb = ((u + 0x8000u) >> 16) & 0x7FFFu;  // round-to-nearest bf16, drop sign
    return ((unsigned)r << 15) | nb;
}
static __device__ __forceinline__ float csr_nrm(unsigned u) {
    return __uint_as_float((u & 0x7FFFu) << 16);
}

// ---------------- per-block bucket histogram (persisted) + global counts ----------
__global__ __launch_bounds__(1024) void k_ghist2(const int* __restrict__ col,
                                                 int* __restrict__ hist2d,
                                                 int* gcnt, int E) {
    __shared__ int hist[NBUK];
    int t = threadIdx.x;
    for (int i = t; i < NBUK; i += 1024) hist[i] = 0;
    __syncthreads();
    int e0 = blockIdx.x * EPB, e1 = min(e0 + EPB, E);
    for (int e = e0 + t; e < e1; e += 1024) atomicAdd(&hist[col[e] >> 8], 1);
    __syncthreads();
    for (int i = t; i < NBUK; i += 1024) {
        int c = hist[i];
        hist2d[blockIdx.x * NBUK + i] = c;
        if (c) atomicAdd(&gcnt[i], c);
    }
}

// ---------------- bucket offsets scan (one block) + zero pool buffers ----------
__global__ __launch_bounds__(256) void k_gscan(const int* __restrict__ gcnt,
                                               int* __restrict__ boff,
                                               float* __restrict__ sums,
                                               float* __restrict__ cntf) {
    __shared__ int sm[256];
    int t = threadIdx.x;
    for (int i = t; i < NG * DIM; i += 256) sums[i] = 0.f;
    if (t < NG) cntf[t] = 0.f;
    int v0 = (2 * t < NBUK) ? gcnt[2 * t] : 0;
    int v1 = (2 * t + 1 < NBUK) ? gcnt[2 * t + 1] : 0;
    int s = v0 + v1;
    sm[t] = s;
    __syncthreads();
    for (int off = 1; off < 256; off <<= 1) {
        int tmp = (t >= off) ? sm[t - off] : 0;
        __syncthreads();
        sm[t] += tmp;
        __syncthreads();
    }
    int run = sm[t] - s;
    if (2 * t < NBUK) boff[2 * t] = run;
    run += v0;
    if (2 * t + 1 < NBUK) boff[2 * t + 1] = run;
    if (t == 255) boff[NBUK] = run + v1;  // == NE
}

// ---------------- per-(block,bucket) base scan + fused x->bf16 cast --------------
__global__ __launch_bounds__(256) void k_colscan(const int* __restrict__ hist2d,
                                                 const int* __restrict__ boff,
                                                 int* __restrict__ base2d,
                                                 const float* __restrict__ x,
                                                 unsigned short* __restrict__ xb) {
    __shared__ int sm[256];
    int b = blockIdx.x, t = threadIdx.x;
    int v0 = (2 * t < NBLK) ? hist2d[(size_t)(2 * t) * NBUK + b] : 0;
    int v1 = (2 * t + 1 < NBLK) ? hist2d[(size_t)(2 * t + 1) * NBUK + b] : 0;
    int s = v0 + v1;
    sm[t] = s;
    __syncthreads();
    for (int off = 1; off < 256; off <<= 1) {
        int tmp = (t >= off) ? sm[t - off] : 0;
        __syncthreads();
        sm[t] += tmp;
        __syncthreads();
    }
    int run = boff[b] + sm[t] - s;
    if (2 * t < NBLK) base2d[(size_t)(2 * t) * NBUK + b] = run;
    run += v0;
    if (2 * t + 1 < NBLK) base2d[(size_t)(2 * t + 1) * NBUK + b] = run;
    // fused cast: block b converts its slice of x (float4 quads)
    const int NQ = NN * DIM / 4;
    const int per = (NQ + NBLK - 1) / NBLK;
    int q0 = b * per, q1 = min(q0 + per, NQ);
    for (int i = q0 + t; i < q1; i += 256) {
        float4 v = ((const float4*)x)[i];
        ushort4 o;
        o.x = bf16bits(v.x);
        o.y = bf16bits(v.y);
        o.z = bf16bits(v.z);
        o.w = bf16bits(v.w);
        ((ushort4*)xb)[i] = o;
    }
}

// ---------------- pass 1 v2: single pass, precomputed bases, no global atomics ----
// binned record: .x = (cl<<17)|row  (cl = col&255, row<2^17), .y = ew bits
__global__ __launch_bounds__(1024) void k_part1v2(const int* __restrict__ row,
                                                  const int* __restrict__ col,
                                                  const float* __restrict__ ew,
                                                  const int* __restrict__ base2d,
                                                  int2* __restrict__ binned, int E) {
    __shared__ int cur[NBUK];
    int t = threadIdx.x;
    for (int i = t; i < NBUK; i += 1024) cur[i] = base2d[(size_t)blockIdx.x * NBUK + i];
    __syncthreads();
    int e0 = blockIdx.x * EPB, e1 = min(e0 + EPB, E);
    for (int e = e0 + t; e < e1; e += 1024) {
        int c = col[e];
        int b = c >> 8, cl = c & 255;
        int p = atomicAdd(&cur[b], 1);
        binned[p] = make_int2((cl << 17) | row[e], __float_as_int(ew[e]));
    }
}

// ---------------- pass 2a: per-bucket degree (fixed-point) + rowptr + dinv --------
__global__ __launch_bounds__(256) void k_p2a(const int2* __restrict__ binned,
                                             const int* __restrict__ boff,
                                             float* __restrict__ dinv,
                                             int* __restrict__ rowptr) {
    int b = blockIdx.x, t = threadIdx.x;
    __shared__ unsigned int dsum[256];
    __shared__ int ncnt[256];
    __shared__ int sm[256];
    dsum[t] = 0;
    ncnt[t] = 0;
    __syncthreads();
    int e0 = boff[b], e1 = boff[b + 1];
    for (int e = e0 + t; e < e1; e += 256) {
        int2 v = binned[e];
        int cl = v.x >> 17;
        atomicAdd(&ncnt[cl], 1);
        unsigned int fx = (unsigned int)__float2uint_rn(__int_as_float(v.y) * 16777216.0f);
        atomicAdd(&dsum[cl], fx);
    }
    __syncthreads();
    int c = ncnt[t];
    sm[t] = c;
    __syncthreads();
    for (int off = 1; off < 256; off <<= 1) {
        int tmp = (t >= off) ? sm[t - off] : 0;
        __syncthreads();
        sm[t] += tmp;
        __syncthreads();
    }
    int node = b * 256 + t;
    if (node < NN) {
        rowptr[node] = e0 + sm[t] - c;
        dinv[node] = rsqrtf(1.0f + (float)dsum[t] * (1.0f / 16777216.0f));
    }
    if (b == 0 && t == 0) rowptr[NN] = NE;
}

// ---------------- pass 2b: per-bucket CSR place (packed 4B records) ----------------
__global__ __launch_bounds__(256) void k_p2b(const int2* __restrict__ binned,
                                             const int* __restrict__ boff,
                                             const float* __restrict__ dinv,
                                             const int* __restrict__ rowptr,
                                             unsigned* __restrict__ csr) {
    int b = blockIdx.x, t = threadIdx.x;
    __shared__ int ncur[256];
    __shared__ float ldin[256];
    int node = b * 256 + t;
    ncur[t] = (node < NN) ? rowptr[node] : 0;
    ldin[t] = (node < NN) ? dinv[node] : 0.f;
    __syncthreads();
    int e0 = boff[b], e1 = boff[b + 1];
    for (int e = e0 + t; e < e1; e += 256) {
        int2 v = binned[e];
        int cl = v.x >> 17, r = v.x & 0x1FFFF;
        float nm = dinv[r] * __int_as_float(v.y) * ldin[cl];
        int p = atomicAdd(&ncur[cl], 1);
        csr[p] = csr_pack(r, nm);
    }
}

// ---------------- fused gather + GEMM: out = bf16(relu((Ahat@h) @ W + b)) ---------
// 16 nodes/block (NN%16==0, grid exact). Gather phase = gather5 structure
// (16 lanes/node, 2 groups, 4-deep csr pipeline). One barrier, then GEMM phase:
// thread (nl=tid>>4, dg=tid&15) computes node nl's dims dg*4..+4 from sX/sW.
__global__ __launch_bounds__(256, 7) void k_gg(const int* __restrict__ rowptr,
                                               const unsigned* __restrict__ csr,
                                               const uint4* __restrict__ h8,
                                               const float* __restrict__ dinv,
                                               const float* __restrict__ W,
                                               const float* __restrict__ b,
                                               ushort4* __restrict__ out) {
    __shared__ float sW[64][64];   // [k][d]
    __shared__ float sX[16][68];   // [node][k], +4 pad
    int tid = threadIdx.x;
#pragma unroll
    for (int i = 0; i < 4; ++i) {
        int q = tid + i * 256;
        ((float4*)&sW[0][0])[q] = ((const float4*)W)[q];
    }
    // ---- gather phase ----
    int node = blockIdx.x * 16 + (tid >> 4);
    int l = tid & 15;
    int g2 = l >> 3, sub = l & 7;
    float acc[8];
#pragma unroll
    for (int i = 0; i < 8; ++i) acc[i] = 0.f;
    if (g2 == 0) {  // self-loop term
        float di = dinv[node];
        float s = di * di;
        uint4 v = h8[(size_t)node * 8 + sub];
        float lo, hi;
        bf2x(v.x, lo, hi); acc[0] = lo * s; acc[1] = hi * s;
        bf2x(v.y, lo, hi); acc[2] = lo * s; acc[3] = hi * s;
        bf2x(v.z, lo, hi); acc[4] = lo * s; acc[5] = hi * s;
        bf2x(v.w, lo, hi); acc[6] = lo * s; acc[7] = hi * s;
    }
    int e1 = rowptr[node + 1];
    int e = rowptr[node] + g2;
    unsigned p[4];
#pragma unroll
    for (int i = 0; i < 4; ++i) {
        p[i] = 0u;
        if (e + 2 * i < e1) p[i] = csr[e + 2 * i];
    }
    while (e < e1) {
        uint4 r[4];
#pragma unroll
        for (int i = 0; i < 4; ++i) {
            r[i] = make_uint4(0u, 0u, 0u, 0u);
            if (e + 2 * i < e1) r[i] = h8[(size_t)(p[i] >> 15) * 8 + sub];
        }
        int en = e + 8;
        unsigned q[4];
#pragma unroll
        for (int i = 0; i < 4; ++i) {
            q[i] = 0u;
            if (en + 2 * i < e1) q[i] = csr[en + 2 * i];
        }
#pragma unroll
        for (int i = 0; i < 4; ++i) {
            float nm = csr_nrm(p[i]);
            float lo, hi;
            bf2x(r[i].x, lo, hi); acc[0] = fmaf(lo, nm, acc[0]); acc[1] = fmaf(hi, nm, acc[1]);
            bf2x(r[i].y, lo, hi); acc[2] = fmaf(lo, nm, acc[2]); acc[3] = fmaf(hi, nm, acc[3]);
            bf2x(r[i].z, lo, hi); acc[4] = fmaf(lo, nm, acc[4]); acc[5] = fmaf(hi, nm, acc[5]);
            bf2x(r[i].w, lo, hi); acc[6] = fmaf(lo, nm, acc[6]); acc[7] = fmaf(hi, nm, acc[7]);
        }
#pragma unroll
        for (int i = 0; i < 4; ++i) p[i] = q[i];
        e = en;
    }
#pragma unroll
    for (int i = 0; i < 8; ++i) acc[i] += __shfl_xor(acc[i], 8);
    if (g2 == 0) {
        int c = tid >> 4;
        *(float4*)&sX[c][sub * 8 + 0] = make_float4(acc[0], acc[1], acc[2], acc[3]);
        *(float4*)&sX[c][sub * 8 + 4] = make_float4(acc[4], acc[5], acc[6], acc[7]);
    }
    __syncthreads();
    // ---- GEMM phase ----
    int nl = tid >> 4, dg = tid & 15;
    float a0 = 0.f, a1 = 0.f, a2 = 0.f, a3 = 0.f;
#pragma unroll 4
    for (int k4 = 0; k4 < 16; ++k4) {
        float4 xr = *(const float4*)&sX[nl][k4 * 4];
        float4 w0 = *(const float4*)&sW[k4 * 4 + 0][dg * 4];
        float4 w1 = *(const float4*)&sW[k4 * 4 + 1][dg * 4];
        float4 w2 = *(const float4*)&sW[k4 * 4 + 2][dg * 4];
        float4 w3 = *(const float4*)&sW[k4 * 4 + 3][dg * 4];
        a0 = fmaf(xr.x, w0.x, a0); a1 = fmaf(xr.x, w0.y, a1);
        a2 = fmaf(xr.x, w0.z, a2); a3 = fmaf(xr.x, w0.w, a3);
        a0 = fmaf(xr.y, w1.x, a0); a1 = fmaf(xr.y, w1.y, a1);
        a2 = fmaf(xr.y, w1.z, a2); a3 = fmaf(xr.y, w1.w, a3);
        a0 = fmaf(xr.z, w2.x, a0); a1 = fmaf(xr.z, w2.y, a1);
        a2 = fmaf(xr.z, w2.z, a2); a3 = fmaf(xr.z, w2.w, a3);
        a0 = fmaf(xr.w, w3.x, a0); a1 = fmaf(xr.w, w3.y, a1);
        a2 = fmaf(xr.w, w3.z, a2); a3 = fmaf(xr.w, w3.w, a3);
    }
    float4 bv = ((const float4*)b)[dg];
    ushort4 o;
    o.x = bf16bits(fmaxf(a0 + bv.x, 0.f));
    o.y = bf16bits(fmaxf(a1 + bv.y, 0.f));
    o.z = bf16bits(fmaxf(a2 + bv.z, 0.f));
    o.w = bf16bits(fmaxf(a3 + bv.w, 0.f));
    out[(size_t)(blockIdx.x * 16 + nl) * 16 + dg] = o;
}

// ---------------- gather v5 (standalone, for last layer): bf16 out ----------------
__global__ __launch_bounds__(256) void k_gather5(const int* __restrict__ rowptr,
                                                 const unsigned* __restrict__ csr,
                                                 const uint4* __restrict__ h8,
                                                 const float* __restrict__ dinv,
                                                 uint4* __restrict__ out, int n) {
    int tid = threadIdx.x;
    int node = blockIdx.x * 16 + (tid >> 4);
    if (node >= n) return;
    int l = tid & 15;
    int g2 = l >> 3, sub = l & 7;
    float acc[8];
#pragma unroll
    for (int i = 0; i < 8; ++i) acc[i] = 0.f;
    if (g2 == 0) {  // self-loop term (added once per node)
        float di = dinv[node];
        float s = di * di;
        uint4 v = h8[(size_t)node * 8 + sub];
        float lo, hi;
        bf2x(v.x, lo, hi); acc[0] = lo * s; acc[1] = hi * s;
        bf2x(v.y, lo, hi); acc[2] = lo * s; acc[3] = hi * s;
        bf2x(v.z, lo, hi); acc[4] = lo * s; acc[5] = hi * s;
        bf2x(v.w, lo, hi); acc[6] = lo * s; acc[7] = hi * s;
    }
    int e1 = rowptr[node + 1];
    int e = rowptr[node] + g2;
    unsigned p[4];
#pragma unroll
    for (int i = 0; i < 4; ++i) {
        p[i] = 0u;
        if (e + 2 * i < e1) p[i] = csr[e + 2 * i];
    }
    while (e < e1) {
        uint4 r[4];
#pragma unroll
        for (int i = 0; i < 4; ++i) {
            r[i] = make_uint4(0u, 0u, 0u, 0u);
            if (e + 2 * i < e1) r[i] = h8[(size_t)(p[i] >> 15) * 8 + sub];
        }
        int en = e + 8;
        unsigned q[4];
#pragma unroll
        for (int i = 0; i < 4; ++i) {
            q[i] = 0u;
            if (en + 2 * i < e1) q[i] = csr[en + 2 * i];
        }
#pragma unroll
        for (int i = 0; i < 4; ++i) {
            float nm = csr_nrm(p[i]);
            float lo, hi;
            bf2x(r[i].x, lo, hi); acc[0] = fmaf(lo, nm, acc[0]); acc[1] = fmaf(hi, nm, acc[1]);
            bf2x(r[i].y, lo, hi); acc[2] = fmaf(lo, nm, acc[2]); acc[3] = fmaf(hi, nm, acc[3]);
            bf2x(r[i].z, lo, hi); acc[4] = fmaf(lo, nm, acc[4]); acc[5] = fmaf(hi, nm, acc[5]);
            bf2x(r[i].w, lo, hi); acc[6] = fmaf(lo, nm, acc[6]); acc[7] = fmaf(hi, nm, acc[7]);
        }
#pragma unroll
        for (int i = 0; i < 4; ++i) p[i] = q[i];
        e = en;
    }
#pragma unroll
    for (int i = 0; i < 8; ++i) acc[i] += __shfl_xor(acc[i], 8);
    if (g2 == 0) {
        uint4 o;
        o.x = ((unsigned int)bf16bits(acc[1]) << 16) | bf16bits(acc[0]);
        o.y = ((unsigned int)bf16bits(acc[3]) << 16) | bf16bits(acc[2]);
        o.z = ((unsigned int)bf16bits(acc[5]) << 16) | bf16bits(acc[4]);
        o.w = ((unsigned int)bf16bits(acc[7]) << 16) | bf16bits(acc[6]);
        out[(size_t)node * 8 + sub] = o;
    }
}

// ---------------- pooling v3: LDS-staged two-level reduction ----------------
#define PB3 512
__global__ __launch_bounds__(256) void k_pool3(const int* __restrict__ batch,
                                               const uint4* __restrict__ h8,
                                               float* sums, float* cnt, int n) {
    __shared__ float gsum[64][65];  // [group-g0][dim], +1 pad
    __shared__ float gcl[64];
    int t = threadIdx.x;
    for (int i = t; i < 64 * 65; i += 256) (&gsum[0][0])[i] = 0.f;
    if (t < 64) gcl[t] = 0.f;
    __syncthreads();
    int base = blockIdx.x * PB3;
    int end = min(base + PB3, n);
    int g0 = batch[base];
    int cl = t >> 3, sub = t & 7;
    float acc[8];
#pragma unroll
    for (int i = 0; i < 8; ++i) acc[i] = 0.f;
    int gcur = -1, runlen = 0;
    for (int node = base + cl; node < end; node += 32) {
        int g = batch[node];
        if (g != gcur) {
            if (gcur >= 0) {
                int gl = gcur - g0;
#pragma unroll
                for (int i = 0; i < 8; ++i) atomicAdd(&gsum[gl][sub * 8 + i], acc[i]);
                if (sub == 0) atomicAdd(&gcl[gl], (float)runlen);
#pragma unroll
                for (int i = 0; i < 8; ++i) acc[i] = 0.f;
            }
            gcur = g;
            runlen = 0;
        }
        uint4 v = h8[(size_t)node * 8 + sub];
        float lo, hi;
        bf2x(v.x, lo, hi); acc[0] += lo; acc[1] += hi;
        bf2x(v.y, lo, hi); acc[2] += lo; acc[3] += hi;
        bf2x(v.z, lo, hi); acc[4] += lo; acc[5] += hi;
        bf2x(v.w, lo, hi); acc[6] += lo; acc[7] += hi;
        runlen++;
    }
    if (gcur >= 0) {
        int gl = gcur - g0;
#pragma unroll
        for (int i = 0; i < 8; ++i) atomicAdd(&gsum[gl][sub * 8 + i], acc[i]);
        if (sub == 0) atomicAdd(&gcl[gl], (float)runlen);
    }
    __syncthreads();
    int g1 = batch[end - 1];
    int ngr = g1 - g0 + 1;
    for (int idx = t; idx < ngr * 64; idx += 256) {
        int gl = idx >> 6, d = idx & 63;
        float v = gsum[gl][d];
        if (v != 0.f) atomicAdd(&sums[(g0 + gl) * DIM + d], v);
    }
    if (t < ngr) {
        float c = gcl[t];
        if (c != 0.f) atomicAdd(&cnt[g0 + t], c);
    }
}

// ---------------- head: mean -> @W2+b2 -> fc1 relu -> fc2 -> out ----------------
__global__ __launch_bounds__(64) void k_head(const float* __restrict__ sums,
                                             const float* __restrict__ cnt,
                                             const float* __restrict__ W2,
                                             const float* __restrict__ b2,
                                             const float* __restrict__ fc1w,
                                             const float* __restrict__ fc1b,
                                             const float* __restrict__ fc2w,
                                             const float* __restrict__ fc2b,
                                             const float* __restrict__ ow,
                                             const float* __restrict__ ob,
                                             float* __restrict__ out) {
    int g = blockIdx.x;
    int t = threadIdx.x;
    __shared__ float gv[64];
    __shared__ float tv[64];
    float c = fmaxf(cnt[g], 1.0f);
    gv[t] = sums[g * DIM + t] / c;
    __syncthreads();
    float acc2 = b2[t];
#pragma unroll
    for (int k = 0; k < 64; ++k) acc2 = fmaf(gv[k], W2[k * 64 + t], acc2);
    tv[t] = acc2;
    __syncthreads();
    float r = 0.0f;
    if (t < 32) {
        float acc = fc1b[t];
#pragma unroll
        for (int k = 0; k < 64; ++k) acc = fmaf(tv[k], fc1w[k * 32 + t], acc);
        acc = fmaxf(acc, 0.0f);
        r = acc * fc2w[t];
    }
#pragma unroll
    for (int off = 16; off; off >>= 1) r += __shfl_down(r, off);
    if (t == 0) out[g] = (r + fc2b[0]) * ow[0] + ob[0];
}

extern "C" void kernel_launch(void* const* d_in, const int* in_sizes, int n_in,
                              void* d_out, int out_size, void* d_ws, size_t ws_size,
                              hipStream_t stream) {
    const float* x   = (const float*)d_in[0];
    const int* eidx  = (const int*)d_in[1];
    const float* ew  = (const float*)d_in[2];
    const int* batch = (const int*)d_in[3];
    const float* W0  = (const float*)d_in[4];
    const float* b0  = (const float*)d_in[5];
    const float* W1  = (const float*)d_in[6];
    const float* b1  = (const float*)d_in[7];
    const float* W2  = (const float*)d_in[8];
    const float* b2  = (const float*)d_in[9];
    const float* fc1w = (const float*)d_in[10];
    const float* fc1b = (const float*)d_in[11];
    const float* fc2w = (const float*)d_in[12];
    const float* fc2b = (const float*)d_in[13];
    const float* ow   = (const float*)d_in[14];
    const float* ob   = (const float*)d_in[15];
    float* out = (float*)d_out;

    const int* row = eidx;
    const int* col = eidx + NE;

    // workspace layout (16B-aligned blocks first)
    char* ws = (char*)d_ws;
    int2* binned           = (int2*)ws;               ws += sizeof(int2) * NE;                 // 12.8MB
    unsigned* csr          = (unsigned*)ws;           ws += sizeof(unsigned) * NE;             // 6.4MB
    __hip_bfloat16* Xb     = (__hip_bfloat16*)ws;     ws += sizeof(__hip_bfloat16) * (size_t)NN * DIM;
    __hip_bfloat16* Hb     = (__hip_bfloat16*)ws;     ws += sizeof(__hip_bfloat16) * (size_t)NN * DIM;
    int*   hist2d          = (int*)ws;                ws += sizeof(int) * (size_t)NBLK * NBUK; // 611KB
    int*   base2d          = (int*)ws;                ws += sizeof(int) * (size_t)NBLK * NBUK; // 611KB
    float* dinv            = (float*)ws;              ws += sizeof(float) * NN;
    int*   rowptr          = (int*)ws;                ws += sizeof(int) * (NN + 1);
    int*   gcnt            = (int*)ws;                ws += sizeof(int) * (NBUK + 1);
    int*   boff            = (int*)ws;                ws += sizeof(int) * (NBUK + 1);
    float* sums            = (float*)ws;              ws += sizeof(float) * NG * DIM;
    float* cntf            = (float*)ws;              ws += sizeof(float) * NG;

    // ---- CSR build: persisted per-block hists + deterministic bases ----
    hipMemsetAsync(gcnt, 0, sizeof(int) * NBUK, stream);
    k_ghist2<<<NBLK, 1024, 0, stream>>>(col, hist2d, gcnt, NE);
    k_gscan<<<1, 256, 0, stream>>>(gcnt, boff, sums, cntf);
    k_colscan<<<NBUK, 256, 0, stream>>>(hist2d, boff, base2d, x, (unsigned short*)Xb);
    k_part1v2<<<NBLK, 1024, 0, stream>>>(row, col, ew, base2d, binned, NE);
    k_p2a<<<NBUK, 256, 0, stream>>>(binned, boff, dinv, rowptr);
    k_p2b<<<NBUK, 256, 0, stream>>>(binned, boff, dinv, rowptr, csr);

    int gg_blocks = NN / 16;  // 6250, exact (NN % 16 == 0)

    // fused layers 0,1: X' = relu((Ahat@X)@W + b), bf16 in/out
    k_gg<<<gg_blocks, 256, 0, stream>>>(rowptr, csr, (const uint4*)Xb, dinv, W0, b0, (ushort4*)Hb);
    k_gg<<<gg_blocks, 256, 0, stream>>>(rowptr, csr, (const uint4*)Hb, dinv, W1, b1, (ushort4*)Xb);

    // layer 2 gather (standalone) -> pool; W2/b2 folded into head
    k_gather5<<<gg_blocks, 256, 0, stream>>>(rowptr, csr, (const uint4*)Xb, dinv, (uint4*)Hb, NN);
    k_pool3<<<(NN + PB3 - 1) / PB3, 256, 0, stream>>>(batch, (const uint4*)Hb, sums, cntf, NN);
    k_head<<<NG, 64, 0, stream>>>(sums, cntf, W2, b2, fc1w, fc1b, fc2w, fc2b, ow, ob, out);
}

// Round 18
// 187.419 us; speedup vs baseline: 2.3073x; 1.0558x over previous
//
#include <hip/hip_runtime.h>
#include <hip/hip_bf16.h>

#define NN 100000
#define NE 1600000
#define DIM 64
#define NG 64

#define NBUK 391      // coarse buckets of 256 nodes: bucket = col >> 8
#define EPB 4096      // edges per pass-1 block
#define NBLK 391      // ceil(NE/EPB)

static __device__ __forceinline__ unsigned short bf16bits(float v) {
    __hip_bfloat16 b = __float2bfloat16(v);
    return *reinterpret_cast<unsigned short*>(&b);
}
static __device__ __forceinline__ float bfbits2f(unsigned short u) {
    unsigned int x = ((unsigned int)u) << 16;
    return __uint_as_float(x);
}
// unpack packed bf16x2 dword -> two floats (lo = even dim, hi = odd dim)
static __device__ __forceinline__ void bf2x(unsigned int u, float& lo, float& hi) {
    lo = __uint_as_float(u << 16);
    hi = __uint_as_float(u & 0xFFFF0000u);
}
// csr pack: row(17 bits) | signless-bf16 ew(15 bits). ew >= 0 always.
static __device__ __forceinline__ unsigned csr_pack(int r, float w) {
    unsigned u = __float_as_uint(w);
    unsigned nb = ((u + 0x8000u) >> 16) & 0x7FFFu;  // round-to-nearest bf16, drop sign
    return ((unsigned)r << 15) | nb;
}
static __device__ __forceinline__ float csr_w(unsigned u) {
    return __uint_as_float((u & 0x7FFFu) << 16);
}

// ---------------- per-block bucket histogram (persisted) + global counts ----------
__global__ __launch_bounds__(1024) void k_ghist2(const int* __restrict__ col,
                                                 int* __restrict__ hist2d,
                                                 int* gcnt, int E) {
    __shared__ int hist[NBUK];
    int t = threadIdx.x;
    for (int i = t; i < NBUK; i += 1024) hist[i] = 0;
    __syncthreads();
    int e0 = blockIdx.x * EPB, e1 = min(e0 + EPB, E);
    for (int e = e0 + t; e < e1; e += 1024) atomicAdd(&hist[col[e] >> 8], 1);
    __syncthreads();
    for (int i = t; i < NBUK; i += 1024) {
        int c = hist[i];
        hist2d[blockIdx.x * NBUK + i] = c;
        if (c) atomicAdd(&gcnt[i], c);
    }
}

// ---------------- bucket offsets scan (one block) + zero pool buffers ----------
__global__ __launch_bounds__(256) void k_gscan(const int* __restrict__ gcnt,
                                               int* __restrict__ boff,
                                               float* __restrict__ sums,
                                               float* __restrict__ cntf) {
    __shared__ int sm[256];
    int t = threadIdx.x;
    for (int i = t; i < NG * DIM; i += 256) sums[i] = 0.f;
    if (t < NG) cntf[t] = 0.f;
    int v0 = (2 * t < NBUK) ? gcnt[2 * t] : 0;
    int v1 = (2 * t + 1 < NBUK) ? gcnt[2 * t + 1] : 0;
    int s = v0 + v1;
    sm[t] = s;
    __syncthreads();
    for (int off = 1; off < 256; off <<= 1) {
        int tmp = (t >= off) ? sm[t - off] : 0;
        __syncthreads();
        sm[t] += tmp;
        __syncthreads();
    }
    int run = sm[t] - s;
    if (2 * t < NBUK) boff[2 * t] = run;
    run += v0;
    if (2 * t + 1 < NBUK) boff[2 * t + 1] = run;
    if (t == 255) boff[NBUK] = run + v1;  // == NE
}

// ---------------- per-(block,bucket) base scan ----------------
__global__ __launch_bounds__(256) void k_colscan(const int* __restrict__ hist2d,
                                                 const int* __restrict__ boff,
                                                 int* __restrict__ base2d) {
    __shared__ int sm[256];
    int b = blockIdx.x, t = threadIdx.x;
    int v0 = (2 * t < NBLK) ? hist2d[(size_t)(2 * t) * NBUK + b] : 0;
    int v1 = (2 * t + 1 < NBLK) ? hist2d[(size_t)(2 * t + 1) * NBUK + b] : 0;
    int s = v0 + v1;
    sm[t] = s;
    __syncthreads();
    for (int off = 1; off < 256; off <<= 1) {
        int tmp = (t >= off) ? sm[t - off] : 0;
        __syncthreads();
        sm[t] += tmp;
        __syncthreads();
    }
    int run = boff[b] + sm[t] - s;
    if (2 * t < NBLK) base2d[(size_t)(2 * t) * NBUK + b] = run;
    run += v0;
    if (2 * t + 1 < NBLK) base2d[(size_t)(2 * t + 1) * NBUK + b] = run;
}

// ---------------- pass 1 v2: single pass, precomputed bases, no global atomics ----
// binned record: .x = (cl<<17)|row  (cl = col&255, row<2^17), .y = ew bits
__global__ __launch_bounds__(1024) void k_part1v2(const int* __restrict__ row,
                                                  const int* __restrict__ col,
                                                  const float* __restrict__ ew,
                                                  const int* __restrict__ base2d,
                                                  int2* __restrict__ binned, int E) {
    __shared__ int cur[NBUK];
    int t = threadIdx.x;
    for (int i = t; i < NBUK; i += 1024) cur[i] = base2d[(size_t)blockIdx.x * NBUK + i];
    __syncthreads();
    int e0 = blockIdx.x * EPB, e1 = min(e0 + EPB, E);
    for (int e = e0 + t; e < e1; e += 1024) {
        int c = col[e];
        int b = c >> 8, cl = c & 255;
        int p = atomicAdd(&cur[b], 1);
        binned[p] = make_int2((cl << 17) | row[e], __float_as_int(ew[e]));
    }
}

// ---------------- fused pass 2: degree+rowptr+dinv, csr place, x->h' cast ----------
// h' = x * dinv (bf16). csr record = pack(row, ew) -- no dinv needed per edge.
__global__ __launch_bounds__(256) void k_p2(const int2* __restrict__ binned,
                                            const int* __restrict__ boff,
                                            float* __restrict__ dinv,
                                            int* __restrict__ rowptr,
                                            unsigned* __restrict__ csr,
                                            const float* __restrict__ x,
                                            unsigned short* __restrict__ xb) {
    int b = blockIdx.x, t = threadIdx.x;
    __shared__ unsigned int dsum[256];
    __shared__ int ncnt[256];
    __shared__ int sm[256];
    __shared__ float ldin[256];
    __shared__ int ncur[256];
    dsum[t] = 0;
    ncnt[t] = 0;
    __syncthreads();
    int e0 = boff[b], e1 = boff[b + 1];
    // pass 1: per-node count + fixed-point weighted degree
    for (int e = e0 + t; e < e1; e += 256) {
        int2 v = binned[e];
        int cl = v.x >> 17;
        atomicAdd(&ncnt[cl], 1);
        unsigned int fx = (unsigned int)__float2uint_rn(__int_as_float(v.y) * 16777216.0f);
        atomicAdd(&dsum[cl], fx);
    }
    __syncthreads();
    int c = ncnt[t];
    sm[t] = c;
    __syncthreads();
    for (int off = 1; off < 256; off <<= 1) {
        int tmp = (t >= off) ? sm[t - off] : 0;
        __syncthreads();
        sm[t] += tmp;
        __syncthreads();
    }
    int node = b * 256 + t;
    float dv = rsqrtf(1.0f + (float)dsum[t] * (1.0f / 16777216.0f));
    int rp = e0 + sm[t] - c;
    ldin[t] = dv;
    ncur[t] = rp;
    if (node < NN) {
        rowptr[node] = rp;
        dinv[node] = dv;
    }
    if (b == 0 && t == 0) rowptr[NN] = NE;
    __syncthreads();
    // pass 2: csr place (binned window is L2-warm)
    for (int e = e0 + t; e < e1; e += 256) {
        int2 v = binned[e];
        int cl = v.x >> 17, r = v.x & 0x1FFFF;
        int p = atomicAdd(&ncur[cl], 1);
        csr[p] = csr_pack(r, __int_as_float(v.y));
    }
    // pass 3: cast this bucket's x rows to h' = x*dinv (bf16), 16 quads/node
    int nfirst = b * 256;
    int nlast = min(nfirst + 256, NN);
    for (int idx = t; idx < (nlast - nfirst) * 16; idx += 256) {
        int nl = idx >> 4, q = idx & 15;
        float dvn = ldin[nl];
        float4 v = ((const float4*)x)[(size_t)(nfirst + nl) * 16 + q];
        ushort4 o;
        o.x = bf16bits(v.x * dvn);
        o.y = bf16bits(v.y * dvn);
        o.z = bf16bits(v.z * dvn);
        o.w = bf16bits(v.w * dvn);
        ((ushort4*)xb)[(size_t)(nfirst + nl) * 16 + q] = o;
    }
}

// ---------------- fused gather + GEMM: out = bf16(relu((Ahat@h) @ W + b) * dinv) ---
// h-input is h' = h*dinv; out = dinv*(h'[n] + sum h'[src]*ew); next-layer h' stored.
__global__ __launch_bounds__(256, 7) void k_gg(const int* __restrict__ rowptr,
                                               const unsigned* __restrict__ csr,
                                               const uint4* __restrict__ h8,
                                               const float* __restrict__ dinv,
                                               const float* __restrict__ W,
                                               const float* __restrict__ b,
                                               ushort4* __restrict__ out) {
    __shared__ float sW[64][64];   // [k][d]
    __shared__ float sX[16][68];   // [node][k], +4 pad
    int tid = threadIdx.x;
#pragma unroll
    for (int i = 0; i < 4; ++i) {
        int q = tid + i * 256;
        ((float4*)&sW[0][0])[q] = ((const float4*)W)[q];
    }
    // ---- gather phase ----
    int node = blockIdx.x * 16 + (tid >> 4);
    int l = tid & 15;
    int g2 = l >> 3, sub = l & 7;
    float dv = dinv[node];
    float acc[8];
#pragma unroll
    for (int i = 0; i < 8; ++i) acc[i] = 0.f;
    if (g2 == 0) {  // self-loop term: coefficient 1 on h'
        uint4 v = h8[(size_t)node * 8 + sub];
        float lo, hi;
        bf2x(v.x, lo, hi); acc[0] = lo; acc[1] = hi;
        bf2x(v.y, lo, hi); acc[2] = lo; acc[3] = hi;
        bf2x(v.z, lo, hi); acc[4] = lo; acc[5] = hi;
        bf2x(v.w, lo, hi); acc[6] = lo; acc[7] = hi;
    }
    int e1 = rowptr[node + 1];
    int e = rowptr[node] + g2;
    unsigned p[4];
#pragma unroll
    for (int i = 0; i < 4; ++i) {
        p[i] = 0u;
        if (e + 2 * i < e1) p[i] = csr[e + 2 * i];
    }
    while (e < e1) {
        uint4 r[4];
#pragma unroll
        for (int i = 0; i < 4; ++i) {
            r[i] = make_uint4(0u, 0u, 0u, 0u);
            if (e + 2 * i < e1) r[i] = h8[(size_t)(p[i] >> 15) * 8 + sub];
        }
        int en = e + 8;
        unsigned q[4];
#pragma unroll
        for (int i = 0; i < 4; ++i) {
            q[i] = 0u;
            if (en + 2 * i < e1) q[i] = csr[en + 2 * i];
        }
#pragma unroll
        for (int i = 0; i < 4; ++i) {
            float nm = csr_w(p[i]);
            float lo, hi;
            bf2x(r[i].x, lo, hi); acc[0] = fmaf(lo, nm, acc[0]); acc[1] = fmaf(hi, nm, acc[1]);
            bf2x(r[i].y, lo, hi); acc[2] = fmaf(lo, nm, acc[2]); acc[3] = fmaf(hi, nm, acc[3]);
            bf2x(r[i].z, lo, hi); acc[4] = fmaf(lo, nm, acc[4]); acc[5] = fmaf(hi, nm, acc[5]);
            bf2x(r[i].w, lo, hi); acc[6] = fmaf(lo, nm, acc[6]); acc[7] = fmaf(hi, nm, acc[7]);
        }
#pragma unroll
        for (int i = 0; i < 4; ++i) p[i] = q[i];
        e = en;
    }
#pragma unroll
    for (int i = 0; i < 8; ++i) acc[i] += __shfl_xor(acc[i], 8);
    if (g2 == 0) {
        int c = tid >> 4;
        // true gathered value = dv * (self + edge sum)
        *(float4*)&sX[c][sub * 8 + 0] = make_float4(acc[0] * dv, acc[1] * dv, acc[2] * dv, acc[3] * dv);
        *(float4*)&sX[c][sub * 8 + 4] = make_float4(acc[4] * dv, acc[5] * dv, acc[6] * dv, acc[7] * dv);
    }
    __syncthreads();
    // ---- GEMM phase ----
    int nl = tid >> 4, dg = tid & 15;
    float a0 = 0.f, a1 = 0.f, a2 = 0.f, a3 = 0.f;
#pragma unroll 4
    for (int k4 = 0; k4 < 16; ++k4) {
        float4 xr = *(const float4*)&sX[nl][k4 * 4];
        float4 w0 = *(const float4*)&sW[k4 * 4 + 0][dg * 4];
        float4 w1 = *(const float4*)&sW[k4 * 4 + 1][dg * 4];
        float4 w2 = *(const float4*)&sW[k4 * 4 + 2][dg * 4];
        float4 w3 = *(const float4*)&sW[k4 * 4 + 3][dg * 4];
        a0 = fmaf(xr.x, w0.x, a0); a1 = fmaf(xr.x, w0.y, a1);
        a2 = fmaf(xr.x, w0.z, a2); a3 = fmaf(xr.x, w0.w, a3);
        a0 = fmaf(xr.y, w1.x, a0); a1 = fmaf(xr.y, w1.y, a1);
        a2 = fmaf(xr.y, w1.z, a2); a3 = fmaf(xr.y, w1.w, a3);
        a0 = fmaf(xr.z, w2.x, a0); a1 = fmaf(xr.z, w2.y, a1);
        a2 = fmaf(xr.z, w2.z, a2); a3 = fmaf(xr.z, w2.w, a3);
        a0 = fmaf(xr.w, w3.x, a0); a1 = fmaf(xr.w, w3.y, a1);
        a2 = fmaf(xr.w, w3.z, a2); a3 = fmaf(xr.w, w3.w, a3);
    }
    float4 bv = ((const float4*)b)[dg];
    ushort4 o;  // store next-layer h' = relu(.)*dv
    o.x = bf16bits(fmaxf(a0 + bv.x, 0.f) * dv);
    o.y = bf16bits(fmaxf(a1 + bv.y, 0.f) * dv);
    o.z = bf16bits(fmaxf(a2 + bv.z, 0.f) * dv);
    o.w = bf16bits(fmaxf(a3 + bv.w, 0.f) * dv);
    out[(size_t)(blockIdx.x * 16 + nl) * 16 + dg] = o;
}

// ---------------- gather v6 (standalone, last layer): true-value bf16 out ---------
__global__ __launch_bounds__(256) void k_gather6(const int* __restrict__ rowptr,
                                                 const unsigned* __restrict__ csr,
                                                 const uint4* __restrict__ h8,
                                                 const float* __restrict__ dinv,
                                                 uint4* __restrict__ out, int n) {
    int tid = threadIdx.x;
    int node = blockIdx.x * 16 + (tid >> 4);
    if (node >= n) return;
    int l = tid & 15;
    int g2 = l >> 3, sub = l & 7;
    float dv = dinv[node];
    float acc[8];
#pragma unroll
    for (int i = 0; i < 8; ++i) acc[i] = 0.f;
    if (g2 == 0) {  // self-loop term
        uint4 v = h8[(size_t)node * 8 + sub];
        float lo, hi;
        bf2x(v.x, lo, hi); acc[0] = lo; acc[1] = hi;
        bf2x(v.y, lo, hi); acc[2] = lo; acc[3] = hi;
        bf2x(v.z, lo, hi); acc[4] = lo; acc[5] = hi;
        bf2x(v.w, lo, hi); acc[6] = lo; acc[7] = hi;
    }
    int e1 = rowptr[node + 1];
    int e = rowptr[node] + g2;
    unsigned p[4];
#pragma unroll
    for (int i = 0; i < 4; ++i) {
        p[i] = 0u;
        if (e + 2 * i < e1) p[i] = csr[e + 2 * i];
    }
    while (e < e1) {
        uint4 r[4];
#pragma unroll
        for (int i = 0; i < 4; ++i) {
            r[i] = make_uint4(0u, 0u, 0u, 0u);
            if (e + 2 * i < e1) r[i] = h8[(size_t)(p[i] >> 15) * 8 + sub];
        }
        int en = e + 8;
        unsigned q[4];
#pragma unroll
        for (int i = 0; i < 4; ++i) {
            q[i] = 0u;
            if (en + 2 * i < e1) q[i] = csr[en + 2 * i];
        }
#pragma unroll
        for (int i = 0; i < 4; ++i) {
            float nm = csr_w(p[i]);
            float lo, hi;
            bf2x(r[i].x, lo, hi); acc[0] = fmaf(lo, nm, acc[0]); acc[1] = fmaf(hi, nm, acc[1]);
            bf2x(r[i].y, lo, hi); acc[2] = fmaf(lo, nm, acc[2]); acc[3] = fmaf(hi, nm, acc[3]);
            bf2x(r[i].z, lo, hi); acc[4] = fmaf(lo, nm, acc[4]); acc[5] = fmaf(hi, nm, acc[5]);
            bf2x(r[i].w, lo, hi); acc[6] = fmaf(lo, nm, acc[6]); acc[7] = fmaf(hi, nm, acc[7]);
        }
#pragma unroll
        for (int i = 0; i < 4; ++i) p[i] = q[i];
        e = en;
    }
#pragma unroll
    for (int i = 0; i < 8; ++i) acc[i] += __shfl_xor(acc[i], 8);
    if (g2 == 0) {
        uint4 o;
        o.x = ((unsigned int)bf16bits(acc[1] * dv) << 16) | bf16bits(acc[0] * dv);
        o.y = ((unsigned int)bf16bits(acc[3] * dv) << 16) | bf16bits(acc[2] * dv);
        o.z = ((unsigned int)bf16bits(acc[5] * dv) << 16) | bf16bits(acc[4] * dv);
        o.w = ((unsigned int)bf16bits(acc[7] * dv) << 16) | bf16bits(acc[6] * dv);
        out[(size_t)node * 8 + sub] = o;
    }
}

// ---------------- pooling v3: LDS-staged two-level reduction ----------------
#define PB3 512
__global__ __launch_bounds__(256) void k_pool3(const int* __restrict__ batch,
                                               const uint4* __restrict__ h8,
                                               float* sums, float* cnt, int n) {
    __shared__ float gsum[64][65];  // [group-g0][dim], +1 pad
    __shared__ float gcl[64];
    int t = threadIdx.x;
    for (int i = t; i < 64 * 65; i += 256) (&gsum[0][0])[i] = 0.f;
    if (t < 64) gcl[t] = 0.f;
    __syncthreads();
    int base = blockIdx.x * PB3;
    int end = min(base + PB3, n);
    int g0 = batch[base];
    int cl = t >> 3, sub = t & 7;
    float acc[8];
#pragma unroll
    for (int i = 0; i < 8; ++i) acc[i] = 0.f;
    int gcur = -1, runlen = 0;
    for (int node = base + cl; node < end; node += 32) {
        int g = batch[node];
        if (g != gcur) {
            if (gcur >= 0) {
                int gl = gcur - g0;
#pragma unroll
                for (int i = 0; i < 8; ++i) atomicAdd(&gsum[gl][sub * 8 + i], acc[i]);
                if (sub == 0) atomicAdd(&gcl[gl], (float)runlen);
#pragma unroll
                for (int i = 0; i < 8; ++i) acc[i] = 0.f;
            }
            gcur = g;
            runlen = 0;
        }
        uint4 v = h8[(size_t)node * 8 + sub];
        float lo, hi;
        bf2x(v.x, lo, hi); acc[0] += lo; acc[1] += hi;
        bf2x(v.y, lo, hi); acc[2] += lo; acc[3] += hi;
        bf2x(v.z, lo, hi); acc[4] += lo; acc[5] += hi;
        bf2x(v.w, lo, hi); acc[6] += lo; acc[7] += hi;
        runlen++;
    }
    if (gcur >= 0) {
        int gl = gcur - g0;
#pragma unroll
        for (int i = 0; i < 8; ++i) atomicAdd(&gsum[gl][sub * 8 + i], acc[i]);
        if (sub == 0) atomicAdd(&gcl[gl], (float)runlen);
    }
    __syncthreads();
    int g1 = batch[end - 1];
    int ngr = g1 - g0 + 1;
    for (int idx = t; idx < ngr * 64; idx += 256) {
        int gl = idx >> 6, d = idx & 63;
        float v = gsum[gl][d];
        if (v != 0.f) atomicAdd(&sums[(g0 + gl) * DIM + d], v);
    }
    if (t < ngr) {
        float c = gcl[t];
        if (c != 0.f) atomicAdd(&cnt[g0 + t], c);
    }
}

// ---------------- head: mean -> @W2+b2 -> fc1 relu -> fc2 -> out ----------------
__global__ __launch_bounds__(64) void k_head(const float* __restrict__ sums,
                                             const float* __restrict__ cnt,
                                             const float* __restrict__ W2,
                                             const float* __restrict__ b2,
                                             const float* __restrict__ fc1w,
                                             const float* __restrict__ fc1b,
                                             const float* __restrict__ fc2w,
                                             const float* __restrict__ fc2b,
                                             const float* __restrict__ ow,
                                             const float* __restrict__ ob,
                                             float* __restrict__ out) {
    int g = blockIdx.x;
    int t = threadIdx.x;
    __shared__ float gv[64];
    __shared__ float tv[64];
    float c = fmaxf(cnt[g], 1.0f);
    gv[t] = sums[g * DIM + t] / c;
    __syncthreads();
    float acc2 = b2[t];
#pragma unroll
    for (int k = 0; k < 64; ++k) acc2 = fmaf(gv[k], W2[k * 64 + t], acc2);
    tv[t] = acc2;
    __syncthreads();
    float r = 0.0f;
    if (t < 32) {
        float acc = fc1b[t];
#pragma unroll
        for (int k = 0; k < 64; ++k) acc = fmaf(tv[k], fc1w[k * 32 + t], acc);
        acc = fmaxf(acc, 0.0f);
        r = acc * fc2w[t];
    }
#pragma unroll
    for (int off = 16; off; off >>= 1) r += __shfl_down(r, off);
    if (t == 0) out[g] = (r + fc2b[0]) * ow[0] + ob[0];
}

extern "C" void kernel_launch(void* const* d_in, const int* in_sizes, int n_in,
                              void* d_out, int out_size, void* d_ws, size_t ws_size,
                              hipStream_t stream) {
    const float* x   = (const float*)d_in[0];
    const int* eidx  = (const int*)d_in[1];
    const float* ew  = (const float*)d_in[2];
    const int* batch = (const int*)d_in[3];
    const float* W0  = (const float*)d_in[4];
    const float* b0  = (const float*)d_in[5];
    const float* W1  = (const float*)d_in[6];
    const float* b1  = (const float*)d_in[7];
    const float* W2  = (const float*)d_in[8];
    const float* b2  = (const float*)d_in[9];
    const float* fc1w = (const float*)d_in[10];
    const float* fc1b = (const float*)d_in[11];
    const float* fc2w = (const float*)d_in[12];
    const float* fc2b = (const float*)d_in[13];
    const float* ow   = (const float*)d_in[14];
    const float* ob   = (const float*)d_in[15];
    float* out = (float*)d_out;

    const int* row = eidx;
    const int* col = eidx + NE;

    // workspace layout (16B-aligned blocks first)
    char* ws = (char*)d_ws;
    int2* binned           = (int2*)ws;               ws += sizeof(int2) * NE;                 // 12.8MB
    unsigned* csr          = (unsigned*)ws;           ws += sizeof(unsigned) * NE;             // 6.4MB
    __hip_bfloat16* Xb     = (__hip_bfloat16*)ws;     ws += sizeof(__hip_bfloat16) * (size_t)NN * DIM;
    __hip_bfloat16* Hb     = (__hip_bfloat16*)ws;     ws += sizeof(__hip_bfloat16) * (size_t)NN * DIM;
    int*   hist2d          = (int*)ws;                ws += sizeof(int) * (size_t)NBLK * NBUK; // 611KB
    int*   base2d          = (int*)ws;                ws += sizeof(int) * (size_t)NBLK * NBUK; // 611KB
    float* dinv            = (float*)ws;              ws += sizeof(float) * NN;
    int*   rowptr          = (int*)ws;                ws += sizeof(int) * (NN + 1);
    int*   gcnt            = (int*)ws;                ws += sizeof(int) * (NBUK + 1);
    int*   boff            = (int*)ws;                ws += sizeof(int) * (NBUK + 1);
    float* sums            = (float*)ws;              ws += sizeof(float) * NG * DIM;
    float* cntf            = (float*)ws;              ws += sizeof(float) * NG;

    // ---- CSR build: persisted per-block hists + deterministic bases ----
    hipMemsetAsync(gcnt, 0, sizeof(int) * NBUK, stream);
    k_ghist2<<<NBLK, 1024, 0, stream>>>(col, hist2d, gcnt, NE);
    k_gscan<<<1, 256, 0, stream>>>(gcnt, boff, sums, cntf);
    k_colscan<<<NBUK, 256, 0, stream>>>(hist2d, boff, base2d);
    k_part1v2<<<NBLK, 1024, 0, stream>>>(row, col, ew, base2d, binned, NE);
    k_p2<<<NBUK, 256, 0, stream>>>(binned, boff, dinv, rowptr, csr, x, (unsigned short*)Xb);

    int gg_blocks = NN / 16;  // 6250, exact (NN % 16 == 0)

    // fused layers 0,1: h' pipeline
    k_gg<<<gg_blocks, 256, 0, stream>>>(rowptr, csr, (const uint4*)Xb, dinv, W0, b0, (ushort4*)Hb);
    k_gg<<<gg_blocks, 256, 0, stream>>>(rowptr, csr, (const uint4*)Hb, dinv, W1, b1, (ushort4*)Xb);

    // layer 2 gather (true values) -> pool; W2/b2 folded into head
    k_gather6<<<gg_blocks, 256, 0, stream>>>(rowptr, csr, (const uint4*)Xb, dinv, (uint4*)Hb, NN);
    k_pool3<<<(NN + PB3 - 1) / PB3, 256, 0, stream>>>(batch, (const uint4*)Hb, sums, cntf, NN);
    k_head<<<NG, 64, 0, stream>>>(sums, cntf, W2, b2, fc1w, fc1b, fc2w, fc2b, ow, ob, out);
}

// Round 19
// 183.109 us; speedup vs baseline: 2.3616x; 1.0235x over previous
//
#include <hip/hip_runtime.h>
#include <hip/hip_bf16.h>

#define NN 100000
#define NE 1600000
#define DIM 64
#define NG 64

#define NBUK 391      // coarse buckets of 256 nodes: bucket = col >> 8
#define EPB 4096      // edges per pass-1 block
#define NBLK 391      // ceil(NE/EPB)

typedef float fvec2 __attribute__((ext_vector_type(2)));

static __device__ __forceinline__ unsigned short bf16bits(float v) {
    __hip_bfloat16 b = __float2bfloat16(v);
    return *reinterpret_cast<unsigned short*>(&b);
}
// fp8 e4m3 (OCP) HW converts: 4 fp8 <-> 4 f32 per dword
static __device__ __forceinline__ void fp8x4(unsigned w, float& a, float& b, float& c, float& d) {
    fvec2 lo = __builtin_amdgcn_cvt_pk_f32_fp8((int)w, false);
    fvec2 hi = __builtin_amdgcn_cvt_pk_f32_fp8((int)w, true);
    a = lo[0]; b = lo[1]; c = hi[0]; d = hi[1];
}
static __device__ __forceinline__ unsigned fp8pack4(float a, float b, float c, float d) {
    int w = __builtin_amdgcn_cvt_pk_fp8_f32(a, b, 0, false);
    w = __builtin_amdgcn_cvt_pk_fp8_f32(c, d, w, true);
    return (unsigned)w;
}
// csr pack: row(17 bits) | signless-bf16 ew(15 bits). ew >= 0 always.
static __device__ __forceinline__ unsigned csr_pack(int r, float w) {
    unsigned u = __float_as_uint(w);
    unsigned nb = ((u + 0x8000u) >> 16) & 0x7FFFu;
    return ((unsigned)r << 15) | nb;
}
static __device__ __forceinline__ float csr_w(unsigned u) {
    return __uint_as_float((u & 0x7FFFu) << 16);
}

// ---------------- per-block bucket histogram (persisted) + global counts ----------
__global__ __launch_bounds__(1024) void k_ghist2(const int* __restrict__ col,
                                                 int* __restrict__ hist2d,
                                                 int* gcnt, int E) {
    __shared__ int hist[NBUK];
    int t = threadIdx.x;
    for (int i = t; i < NBUK; i += 1024) hist[i] = 0;
    __syncthreads();
    int e0 = blockIdx.x * EPB, e1 = min(e0 + EPB, E);
    for (int e = e0 + t; e < e1; e += 1024) atomicAdd(&hist[col[e] >> 8], 1);
    __syncthreads();
    for (int i = t; i < NBUK; i += 1024) {
        int c = hist[i];
        hist2d[blockIdx.x * NBUK + i] = c;
        if (c) atomicAdd(&gcnt[i], c);
    }
}

// ---------------- bucket offsets scan (one block) + zero pool buffers ----------
__global__ __launch_bounds__(256) void k_gscan(const int* __restrict__ gcnt,
                                               int* __restrict__ boff,
                                               float* __restrict__ sums,
                                               float* __restrict__ cntf) {
    __shared__ int sm[256];
    int t = threadIdx.x;
    for (int i = t; i < NG * DIM; i += 256) sums[i] = 0.f;
    if (t < NG) cntf[t] = 0.f;
    int v0 = (2 * t < NBUK) ? gcnt[2 * t] : 0;
    int v1 = (2 * t + 1 < NBUK) ? gcnt[2 * t + 1] : 0;
    int s = v0 + v1;
    sm[t] = s;
    __syncthreads();
    for (int off = 1; off < 256; off <<= 1) {
        int tmp = (t >= off) ? sm[t - off] : 0;
        __syncthreads();
        sm[t] += tmp;
        __syncthreads();
    }
    int run = sm[t] - s;
    if (2 * t < NBUK) boff[2 * t] = run;
    run += v0;
    if (2 * t + 1 < NBUK) boff[2 * t + 1] = run;
    if (t == 255) boff[NBUK] = run + v1;  // == NE
}

// ---------------- per-(block,bucket) base scan ----------------
__global__ __launch_bounds__(256) void k_colscan(const int* __restrict__ hist2d,
                                                 const int* __restrict__ boff,
                                                 int* __restrict__ base2d) {
    __shared__ int sm[256];
    int b = blockIdx.x, t = threadIdx.x;
    int v0 = (2 * t < NBLK) ? hist2d[(size_t)(2 * t) * NBUK + b] : 0;
    int v1 = (2 * t + 1 < NBLK) ? hist2d[(size_t)(2 * t + 1) * NBUK + b] : 0;
    int s = v0 + v1;
    sm[t] = s;
    __syncthreads();
    for (int off = 1; off < 256; off <<= 1) {
        int tmp = (t >= off) ? sm[t - off] : 0;
        __syncthreads();
        sm[t] += tmp;
        __syncthreads();
    }
    int run = boff[b] + sm[t] - s;
    if (2 * t < NBLK) base2d[(size_t)(2 * t) * NBUK + b] = run;
    run += v0;
    if (2 * t + 1 < NBLK) base2d[(size_t)(2 * t + 1) * NBUK + b] = run;
}

// ---------------- pass 1 v2: single pass, precomputed bases, no global atomics ----
// binned record: .x = (cl<<17)|row  (cl = col&255, row<2^17), .y = ew bits
__global__ __launch_bounds__(1024) void k_part1v2(const int* __restrict__ row,
                                                  const int* __restrict__ col,
                                                  const float* __restrict__ ew,
                                                  const int* __restrict__ base2d,
                                                  int2* __restrict__ binned, int E) {
    __shared__ int cur[NBUK];
    int t = threadIdx.x;
    for (int i = t; i < NBUK; i += 1024) cur[i] = base2d[(size_t)blockIdx.x * NBUK + i];
    __syncthreads();
    int e0 = blockIdx.x * EPB, e1 = min(e0 + EPB, E);
    for (int e = e0 + t; e < e1; e += 1024) {
        int c = col[e];
        int b = c >> 8, cl = c & 255;
        int p = atomicAdd(&cur[b], 1);
        binned[p] = make_int2((cl << 17) | row[e], __float_as_int(ew[e]));
    }
}

// ---------------- fused pass 2: degree+rowptr+dinv, csr place, x->h' cast (fp8) ----
__global__ __launch_bounds__(256) void k_p2(const int2* __restrict__ binned,
                                            const int* __restrict__ boff,
                                            float* __restrict__ dinv,
                                            int* __restrict__ rowptr,
                                            unsigned* __restrict__ csr,
                                            const float* __restrict__ x,
                                            unsigned* __restrict__ xb) {
    int b = blockIdx.x, t = threadIdx.x;
    __shared__ unsigned int dsum[256];
    __shared__ int ncnt[256];
    __shared__ int sm[256];
    __shared__ float ldin[256];
    __shared__ int ncur[256];
    dsum[t] = 0;
    ncnt[t] = 0;
    __syncthreads();
    int e0 = boff[b], e1 = boff[b + 1];
    for (int e = e0 + t; e < e1; e += 256) {
        int2 v = binned[e];
        int cl = v.x >> 17;
        atomicAdd(&ncnt[cl], 1);
        unsigned int fx = (unsigned int)__float2uint_rn(__int_as_float(v.y) * 16777216.0f);
        atomicAdd(&dsum[cl], fx);
    }
    __syncthreads();
    int c = ncnt[t];
    sm[t] = c;
    __syncthreads();
    for (int off = 1; off < 256; off <<= 1) {
        int tmp = (t >= off) ? sm[t - off] : 0;
        __syncthreads();
        sm[t] += tmp;
        __syncthreads();
    }
    int node = b * 256 + t;
    float dv = rsqrtf(1.0f + (float)dsum[t] * (1.0f / 16777216.0f));
    int rp = e0 + sm[t] - c;
    ldin[t] = dv;
    ncur[t] = rp;
    if (node < NN) {
        rowptr[node] = rp;
        dinv[node] = dv;
    }
    if (b == 0 && t == 0) rowptr[NN] = NE;
    __syncthreads();
    // csr place (binned window L2-warm)
    for (int e = e0 + t; e < e1; e += 256) {
        int2 v = binned[e];
        int cl = v.x >> 17, r = v.x & 0x1FFFF;
        int p = atomicAdd(&ncur[cl], 1);
        csr[p] = csr_pack(r, __int_as_float(v.y));
    }
    // cast this bucket's x rows to h' = x*dinv (fp8), 16 dwords/node
    int nfirst = b * 256;
    int nlast = min(nfirst + 256, NN);
    for (int idx = t; idx < (nlast - nfirst) * 16; idx += 256) {
        int nl = idx >> 4, q = idx & 15;
        float dvn = ldin[nl];
        float4 v = ((const float4*)x)[(size_t)(nfirst + nl) * 16 + q];
        xb[(size_t)(nfirst + nl) * 16 + q] =
            fp8pack4(v.x * dvn, v.y * dvn, v.z * dvn, v.w * dvn);
    }
}

// ---------------- fused gather + GEMM (fp8 h'): out = fp8(relu(g@W+b)*dinv) -------
__global__ __launch_bounds__(256, 7) void k_gg(const int* __restrict__ rowptr,
                                               const unsigned* __restrict__ csr,
                                               const uint2* __restrict__ hf8,
                                               const float* __restrict__ dinv,
                                               const float* __restrict__ W,
                                               const float* __restrict__ b,
                                               unsigned* __restrict__ out) {
    __shared__ float sW[64][64];   // [k][d]
    __shared__ float sX[16][68];   // [node][k], +4 pad
    int tid = threadIdx.x;
#pragma unroll
    for (int i = 0; i < 4; ++i) {
        int q = tid + i * 256;
        ((float4*)&sW[0][0])[q] = ((const float4*)W)[q];
    }
    // ---- gather phase ----
    int node = blockIdx.x * 16 + (tid >> 4);
    int l = tid & 15;
    int g2 = l >> 3, sub = l & 7;
    float dv = dinv[node];
    float acc[8];
#pragma unroll
    for (int i = 0; i < 8; ++i) acc[i] = 0.f;
    if (g2 == 0) {  // self-loop term
        uint2 v = hf8[(size_t)node * 8 + sub];
        fp8x4(v.x, acc[0], acc[1], acc[2], acc[3]);
        fp8x4(v.y, acc[4], acc[5], acc[6], acc[7]);
    }
    int e1 = rowptr[node + 1];
    int e = rowptr[node] + g2;
    unsigned p[4];
#pragma unroll
    for (int i = 0; i < 4; ++i) {
        p[i] = 0u;
        if (e + 2 * i < e1) p[i] = csr[e + 2 * i];
    }
    while (e < e1) {
        uint2 r[4];
#pragma unroll
        for (int i = 0; i < 4; ++i) {
            r[i] = make_uint2(0u, 0u);
            if (e + 2 * i < e1) r[i] = hf8[(size_t)(p[i] >> 15) * 8 + sub];
        }
        int en = e + 8;
        unsigned q[4];
#pragma unroll
        for (int i = 0; i < 4; ++i) {
            q[i] = 0u;
            if (en + 2 * i < e1) q[i] = csr[en + 2 * i];
        }
#pragma unroll
        for (int i = 0; i < 4; ++i) {
            float nm = csr_w(p[i]);
            float f0, f1, f2, f3, f4, f5, f6, f7;
            fp8x4(r[i].x, f0, f1, f2, f3);
            fp8x4(r[i].y, f4, f5, f6, f7);
            acc[0] = fmaf(f0, nm, acc[0]); acc[1] = fmaf(f1, nm, acc[1]);
            acc[2] = fmaf(f2, nm, acc[2]); acc[3] = fmaf(f3, nm, acc[3]);
            acc[4] = fmaf(f4, nm, acc[4]); acc[5] = fmaf(f5, nm, acc[5]);
            acc[6] = fmaf(f6, nm, acc[6]); acc[7] = fmaf(f7, nm, acc[7]);
        }
#pragma unroll
        for (int i = 0; i < 4; ++i) p[i] = q[i];
        e = en;
    }
#pragma unroll
    for (int i = 0; i < 8; ++i) acc[i] += __shfl_xor(acc[i], 8);
    if (g2 == 0) {
        int c = tid >> 4;
        *(float4*)&sX[c][sub * 8 + 0] = make_float4(acc[0] * dv, acc[1] * dv, acc[2] * dv, acc[3] * dv);
        *(float4*)&sX[c][sub * 8 + 4] = make_float4(acc[4] * dv, acc[5] * dv, acc[6] * dv, acc[7] * dv);
    }
    __syncthreads();
    // ---- GEMM phase ----
    int nl = tid >> 4, dg = tid & 15;
    float a0 = 0.f, a1 = 0.f, a2 = 0.f, a3 = 0.f;
#pragma unroll 4
    for (int k4 = 0; k4 < 16; ++k4) {
        float4 xr = *(const float4*)&sX[nl][k4 * 4];
        float4 w0 = *(const float4*)&sW[k4 * 4 + 0][dg * 4];
        float4 w1 = *(const float4*)&sW[k4 * 4 + 1][dg * 4];
        float4 w2 = *(const float4*)&sW[k4 * 4 + 2][dg * 4];
        float4 w3 = *(const float4*)&sW[k4 * 4 + 3][dg * 4];
        a0 = fmaf(xr.x, w0.x, a0); a1 = fmaf(xr.x, w0.y, a1);
        a2 = fmaf(xr.x, w0.z, a2); a3 = fmaf(xr.x, w0.w, a3);
        a0 = fmaf(xr.y, w1.x, a0); a1 = fmaf(xr.y, w1.y, a1);
        a2 = fmaf(xr.y, w1.z, a2); a3 = fmaf(xr.y, w1.w, a3);
        a0 = fmaf(xr.z, w2.x, a0); a1 = fmaf(xr.z, w2.y, a1);
        a2 = fmaf(xr.z, w2.z, a2); a3 = fmaf(xr.z, w2.w, a3);
        a0 = fmaf(xr.w, w3.x, a0); a1 = fmaf(xr.w, w3.y, a1);
        a2 = fmaf(xr.w, w3.z, a2); a3 = fmaf(xr.w, w3.w, a3);
    }
    float4 bv = ((const float4*)b)[dg];
    // store next-layer h' = relu(.)*dv as fp8
    out[(size_t)(blockIdx.x * 16 + nl) * 16 + dg] =
        fp8pack4(fmaxf(a0 + bv.x, 0.f) * dv, fmaxf(a1 + bv.y, 0.f) * dv,
                 fmaxf(a2 + bv.z, 0.f) * dv, fmaxf(a3 + bv.w, 0.f) * dv);
}

// ---------------- gather v7 (last layer): fp8 in, true-value bf16 out -------------
__global__ __launch_bounds__(256) void k_gather7(const int* __restrict__ rowptr,
                                                 const unsigned* __restrict__ csr,
                                                 const uint2* __restrict__ hf8,
                                                 const float* __restrict__ dinv,
                                                 uint4* __restrict__ out, int n) {
    int tid = threadIdx.x;
    int node = blockIdx.x * 16 + (tid >> 4);
    if (node >= n) return;
    int l = tid & 15;
    int g2 = l >> 3, sub = l & 7;
    float dv = dinv[node];
    float acc[8];
#pragma unroll
    for (int i = 0; i < 8; ++i) acc[i] = 0.f;
    if (g2 == 0) {  // self-loop term
        uint2 v = hf8[(size_t)node * 8 + sub];
        fp8x4(v.x, acc[0], acc[1], acc[2], acc[3]);
        fp8x4(v.y, acc[4], acc[5], acc[6], acc[7]);
    }
    int e1 = rowptr[node + 1];
    int e = rowptr[node] + g2;
    unsigned p[4];
#pragma unroll
    for (int i = 0; i < 4; ++i) {
        p[i] = 0u;
        if (e + 2 * i < e1) p[i] = csr[e + 2 * i];
    }
    while (e < e1) {
        uint2 r[4];
#pragma unroll
        for (int i = 0; i < 4; ++i) {
            r[i] = make_uint2(0u, 0u);
            if (e + 2 * i < e1) r[i] = hf8[(size_t)(p[i] >> 15) * 8 + sub];
        }
        int en = e + 8;
        unsigned q[4];
#pragma unroll
        for (int i = 0; i < 4; ++i) {
            q[i] = 0u;
            if (en + 2 * i < e1) q[i] = csr[en + 2 * i];
        }
#pragma unroll
        for (int i = 0; i < 4; ++i) {
            float nm = csr_w(p[i]);
            float f0, f1, f2, f3, f4, f5, f6, f7;
            fp8x4(r[i].x, f0, f1, f2, f3);
            fp8x4(r[i].y, f4, f5, f6, f7);
            acc[0] = fmaf(f0, nm, acc[0]); acc[1] = fmaf(f1, nm, acc[1]);
            acc[2] = fmaf(f2, nm, acc[2]); acc[3] = fmaf(f3, nm, acc[3]);
            acc[4] = fmaf(f4, nm, acc[4]); acc[5] = fmaf(f5, nm, acc[5]);
            acc[6] = fmaf(f6, nm, acc[6]); acc[7] = fmaf(f7, nm, acc[7]);
        }
#pragma unroll
        for (int i = 0; i < 4; ++i) p[i] = q[i];
        e = en;
    }
#pragma unroll
    for (int i = 0; i < 8; ++i) acc[i] += __shfl_xor(acc[i], 8);
    if (g2 == 0) {
        uint4 o;
        o.x = ((unsigned int)bf16bits(acc[1] * dv) << 16) | bf16bits(acc[0] * dv);
        o.y = ((unsigned int)bf16bits(acc[3] * dv) << 16) | bf16bits(acc[2] * dv);
        o.z = ((unsigned int)bf16bits(acc[5] * dv) << 16) | bf16bits(acc[4] * dv);
        o.w = ((unsigned int)bf16bits(acc[7] * dv) << 16) | bf16bits(acc[6] * dv);
        out[(size_t)node * 8 + sub] = o;
    }
}

// unpack packed bf16x2 dword -> two floats (pool input)
static __device__ __forceinline__ void bf2x(unsigned int u, float& lo, float& hi) {
    lo = __uint_as_float(u << 16);
    hi = __uint_as_float(u & 0xFFFF0000u);
}

// ---------------- pooling v3: LDS-staged two-level reduction ----------------
#define PB3 512
__global__ __launch_bounds__(256) void k_pool3(const int* __restrict__ batch,
                                               const uint4* __restrict__ h8,
                                               float* sums, float* cnt, int n) {
    __shared__ float gsum[64][65];  // [group-g0][dim], +1 pad
    __shared__ float gcl[64];
    int t = threadIdx.x;
    for (int i = t; i < 64 * 65; i += 256) (&gsum[0][0])[i] = 0.f;
    if (t < 64) gcl[t] = 0.f;
    __syncthreads();
    int base = blockIdx.x * PB3;
    int end = min(base + PB3, n);
    int g0 = batch[base];
    int cl = t >> 3, sub = t & 7;
    float acc[8];
#pragma unroll
    for (int i = 0; i < 8; ++i) acc[i] = 0.f;
    int gcur = -1, runlen = 0;
    for (int node = base + cl; node < end; node += 32) {
        int g = batch[node];
        if (g != gcur) {
            if (gcur >= 0) {
                int gl = gcur - g0;
#pragma unroll
                for (int i = 0; i < 8; ++i) atomicAdd(&gsum[gl][sub * 8 + i], acc[i]);
                if (sub == 0) atomicAdd(&gcl[gl], (float)runlen);
#pragma unroll
                for (int i = 0; i < 8; ++i) acc[i] = 0.f;
            }
            gcur = g;
            runlen = 0;
        }
        uint4 v = h8[(size_t)node * 8 + sub];
        float lo, hi;
        bf2x(v.x, lo, hi); acc[0] += lo; acc[1] += hi;
        bf2x(v.y, lo, hi); acc[2] += lo; acc[3] += hi;
        bf2x(v.z, lo, hi); acc[4] += lo; acc[5] += hi;
        bf2x(v.w, lo, hi); acc[6] += lo; acc[7] += hi;
        runlen++;
    }
    if (gcur >= 0) {
        int gl = gcur - g0;
#pragma unroll
        for (int i = 0; i < 8; ++i) atomicAdd(&gsum[gl][sub * 8 + i], acc[i]);
        if (sub == 0) atomicAdd(&gcl[gl], (float)runlen);
    }
    __syncthreads();
    int g1 = batch[end - 1];
    int ngr = g1 - g0 + 1;
    for (int idx = t; idx < ngr * 64; idx += 256) {
        int gl = idx >> 6, d = idx & 63;
        float v = gsum[gl][d];
        if (v != 0.f) atomicAdd(&sums[(g0 + gl) * DIM + d], v);
    }
    if (t < ngr) {
        float c = gcl[t];
        if (c != 0.f) atomicAdd(&cnt[g0 + t], c);
    }
}

// ---------------- head: mean -> @W2+b2 -> fc1 relu -> fc2 -> out ----------------
__global__ __launch_bounds__(64) void k_head(const float* __restrict__ sums,
                                             const float* __restrict__ cnt,
                                             const float* __restrict__ W2,
                                             const float* __restrict__ b2,
                                             const float* __restrict__ fc1w,
                                             const float* __restrict__ fc1b,
                                             const float* __restrict__ fc2w,
                                             const float* __restrict__ fc2b,
                                             const float* __restrict__ ow,
                                             const float* __restrict__ ob,
                                             float* __restrict__ out) {
    int g = blockIdx.x;
    int t = threadIdx.x;
    __shared__ float gv[64];
    __shared__ float tv[64];
    float c = fmaxf(cnt[g], 1.0f);
    gv[t] = sums[g * DIM + t] / c;
    __syncthreads();
    float acc2 = b2[t];
#pragma unroll
    for (int k = 0; k < 64; ++k) acc2 = fmaf(gv[k], W2[k * 64 + t], acc2);
    tv[t] = acc2;
    __syncthreads();
    float r = 0.0f;
    if (t < 32) {
        float acc = fc1b[t];
#pragma unroll
        for (int k = 0; k < 64; ++k) acc = fmaf(tv[k], fc1w[k * 32 + t], acc);
        acc = fmaxf(acc, 0.0f);
        r = acc * fc2w[t];
    }
#pragma unroll
    for (int off = 16; off; off >>= 1) r += __shfl_down(r, off);
    if (t == 0) out[g] = (r + fc2b[0]) * ow[0] + ob[0];
}

extern "C" void kernel_launch(void* const* d_in, const int* in_sizes, int n_in,
                              void* d_out, int out_size, void* d_ws, size_t ws_size,
                              hipStream_t stream) {
    const float* x   = (const float*)d_in[0];
    const int* eidx  = (const int*)d_in[1];
    const float* ew  = (const float*)d_in[2];
    const int* batch = (const int*)d_in[3];
    const float* W0  = (const float*)d_in[4];
    const float* b0  = (const float*)d_in[5];
    const float* W1  = (const float*)d_in[6];
    const float* b1  = (const float*)d_in[7];
    const float* W2  = (const float*)d_in[8];
    const float* b2  = (const float*)d_in[9];
    const float* fc1w = (const float*)d_in[10];
    const float* fc1b = (const float*)d_in[11];
    const float* fc2w = (const float*)d_in[12];
    const float* fc2b = (const float*)d_in[13];
    const float* ow   = (const float*)d_in[14];
    const float* ob   = (const float*)d_in[15];
    float* out = (float*)d_out;

    const int* row = eidx;
    const int* col = eidx + NE;

    // workspace layout (16B-aligned blocks first)
    char* ws = (char*)d_ws;
    int2* binned           = (int2*)ws;               ws += sizeof(int2) * NE;                 // 12.8MB
    unsigned* csr          = (unsigned*)ws;           ws += sizeof(unsigned) * NE;             // 6.4MB
    unsigned* Xf8          = (unsigned*)ws;           ws += sizeof(unsigned) * (size_t)NN * 16; // 6.4MB fp8
    unsigned* Hf8          = (unsigned*)ws;           ws += sizeof(unsigned) * (size_t)NN * 16; // 6.4MB fp8
    __hip_bfloat16* Hb16   = (__hip_bfloat16*)ws;     ws += sizeof(__hip_bfloat16) * (size_t)NN * DIM; // 12.8MB
    int*   hist2d          = (int*)ws;                ws += sizeof(int) * (size_t)NBLK * NBUK; // 611KB
    int*   base2d          = (int*)ws;                ws += sizeof(int) * (size_t)NBLK * NBUK; // 611KB
    float* dinv            = (float*)ws;              ws += sizeof(float) * NN;
    int*   rowptr          = (int*)ws;                ws += sizeof(int) * (NN + 1);
    int*   gcnt            = (int*)ws;                ws += sizeof(int) * (NBUK + 1);
    int*   boff            = (int*)ws;                ws += sizeof(int) * (NBUK + 1);
    float* sums            = (float*)ws;              ws += sizeof(float) * NG * DIM;
    float* cntf            = (float*)ws;              ws += sizeof(float) * NG;

    // ---- CSR build: persisted per-block hists + deterministic bases ----
    hipMemsetAsync(gcnt, 0, sizeof(int) * NBUK, stream);
    k_ghist2<<<NBLK, 1024, 0, stream>>>(col, hist2d, gcnt, NE);
    k_gscan<<<1, 256, 0, stream>>>(gcnt, boff, sums, cntf);
    k_colscan<<<NBUK, 256, 0, stream>>>(hist2d, boff, base2d);
    k_part1v2<<<NBLK, 1024, 0, stream>>>(row, col, ew, base2d, binned, NE);
    k_p2<<<NBUK, 256, 0, stream>>>(binned, boff, dinv, rowptr, csr, x, Xf8);

    int gg_blocks = NN / 16;  // 6250, exact (NN % 16 == 0)

    // fused layers 0,1: fp8 h' pipeline
    k_gg<<<gg_blocks, 256, 0, stream>>>(rowptr, csr, (const uint2*)Xf8, dinv, W0, b0, Hf8);
    k_gg<<<gg_blocks, 256, 0, stream>>>(rowptr, csr, (const uint2*)Hf8, dinv, W1, b1, Xf8);

    // layer 2 gather (fp8 in, true-value bf16 out) -> pool; W2/b2 folded into head
    k_gather7<<<gg_blocks, 256, 0, stream>>>(rowptr, csr, (const uint2*)Xf8, dinv, (uint4*)Hb16, NN);
    k_pool3<<<(NN + PB3 - 1) / PB3, 256, 0, stream>>>(batch, (const uint4*)Hb16, sums, cntf, NN);
    k_head<<<NG, 64, 0, stream>>>(sums, cntf, W2, b2, fc1w, fc1b, fc2w, fc2b, ow, ob, out);
}